// Round 14
// baseline (299.664 us; speedup 1.0000x reference)
//
#include <hip/hip_runtime.h>
#include <hip/hip_bf16.h>
#include <math.h>

#define N_NODES 20000
#define EMB 128
#define HID 64
#define RELS 8
#define CLS 16
#define N_EDGES 640000
#define NEG 0.2f
#define NKEYS (N_NODES * RELS)
#define SCAN_CHUNK 1024
#define SCAN_NBLK ((NKEYS + SCAN_CHUNK - 1) / SCAN_CHUNK)  // 157
#define S1ROWS 8

typedef unsigned short ushort_t;
typedef __attribute__((ext_vector_type(8))) short bf16x8;
typedef __attribute__((ext_vector_type(8))) unsigned short ushort8_t;
typedef __attribute__((ext_vector_type(4))) unsigned short ushort4_t;
typedef __attribute__((ext_vector_type(4))) float f32x4;

__device__ __forceinline__ float b2f(ushort_t u) {
    return __uint_as_float(((unsigned int)u) << 16);
}
__device__ __forceinline__ ushort_t f2b(float f) {
    __hip_bfloat16 h = __float2bfloat16(f);
    return *reinterpret_cast<ushort_t*>(&h);
}

__device__ __forceinline__ void gload_lds16(const ushort_t* g, ushort_t* l) {
    __builtin_amdgcn_global_load_lds((const __attribute__((address_space(1))) void*)g,
                                     (__attribute__((address_space(3))) void*)l, 16, 0, 0);
}

// ---------------- merged precompute: cvt + wqk1 + wqk2 + wagg1 + wagg2 ----------------
__device__ __forceinline__ void prep_cvt(int i, const float* __restrict__ in, ushort_t* __restrict__ outp) {
    float4 v = *(const float4*)&in[(size_t)i * 4];
    ushort4 o;
    o.x = f2b(v.x); o.y = f2b(v.y); o.z = f2b(v.z); o.w = f2b(v.w);
    *(ushort4*)&outp[(size_t)i * 4] = o;
}

template <int D, int OUT>
__device__ __forceinline__ void prep_wqk(int tid, const float* __restrict__ w, const float* __restrict__ q,
                                         const float* __restrict__ k, ushort_t* __restrict__ wqkt) {
    int c = tid / D, i = tid % D;
    int r = c / 6, j = c % 6;
    const float* qk = (j < 3) ? q : k;
    int jj = (j < 3) ? j : j - 3;
    const float* wrow = w + ((size_t)r * D + i) * OUT;
    float s = 0.f;
    for (int o = 0; o < OUT; o++) s += wrow[o] * qk[o * 3 + jj];
    wqkt[(size_t)c * D + i] = f2b(s);
}

template <int D, int OC>
__device__ __forceinline__ void prep_wagg(int tid, const float* __restrict__ w, ushort_t* __restrict__ outp) {
    const int KT = RELS * 3 * D;
    int kidx = tid % KT;
    int o = tid / KT;
    int r = kidx / (3 * D), h = (kidx / D) % 3, i = kidx % D;
    outp[tid] = f2b(w[((size_t)r * D + i) * (3 * OC) + h * OC + o]);
}

#define PREP_N0 (N_NODES * EMB / 4)
#define PREP_N1 (48 * 128)
#define PREP_N2 (48 * 64)
#define PREP_N3 (64 * 3072)
#define PREP_N4 (16 * 1536)
#define PREP_TOT (PREP_N0 + PREP_N1 + PREP_N2 + PREP_N3 + PREP_N4)

__global__ __launch_bounds__(256) void k_prep(const float* __restrict__ emb, ushort_t* __restrict__ emb_b,
                                              const float* __restrict__ w1, const float* __restrict__ q1,
                                              const float* __restrict__ k1, ushort_t* __restrict__ wqkt1,
                                              const float* __restrict__ w2, const float* __restrict__ q2,
                                              const float* __restrict__ k2, ushort_t* __restrict__ wqkt2,
                                              ushort_t* __restrict__ wagg1, ushort_t* __restrict__ wagg2) {
    int tid = blockIdx.x * 256 + threadIdx.x;
    if (tid < PREP_N0) { prep_cvt(tid, emb, emb_b); return; }
    tid -= PREP_N0;
    if (tid < PREP_N1) { prep_wqk<128, 192>(tid, w1, q1, k1, wqkt1); return; }
    tid -= PREP_N1;
    if (tid < PREP_N2) { prep_wqk<64, 48>(tid, w2, q2, k2, wqkt2); return; }
    tid -= PREP_N2;
    if (tid < PREP_N3) { prep_wagg<128, 64>(tid, w1, wagg1); return; }
    tid -= PREP_N3;
    if (tid < PREP_N4) { prep_wagg<64, 16>(tid, w2, wagg2); return; }
}

// ---------------- CSR build over keys = dst*8 + rel ----------------
__global__ __launch_bounds__(256) void k_count(const int* __restrict__ dst, const int* __restrict__ et,
                                               int* __restrict__ counts) {
    int e = blockIdx.x * blockDim.x + threadIdx.x;
    if (e < N_EDGES) atomicAdd(&counts[dst[e] * 8 + et[e]], 1);
}

__global__ __launch_bounds__(256) void k_scanA(const int* __restrict__ counts, int* __restrict__ keyoff,
                                               int* __restrict__ blocksum) {
    __shared__ int part[256];
    int b = blockIdx.x, tid = threadIdx.x;
    int base = b * SCAN_CHUNK + tid * 4;
    int4 c = make_int4(0, 0, 0, 0);
    if (base + 3 < NKEYS) c = *(const int4*)&counts[base];
    else {
        if (base + 0 < NKEYS) c.x = counts[base + 0];
        if (base + 1 < NKEYS) c.y = counts[base + 1];
        if (base + 2 < NKEYS) c.z = counts[base + 2];
        if (base + 3 < NKEYS) c.w = counts[base + 3];
    }
    int s = c.x + c.y + c.z + c.w;
    part[tid] = s;
    __syncthreads();
    for (int off = 1; off < 256; off <<= 1) {
        int v = (tid >= off) ? part[tid - off] : 0;
        __syncthreads();
        part[tid] += v;
        __syncthreads();
    }
    int excl = part[tid] - s;
    int4 o;
    o.x = excl;
    o.y = excl + c.x;
    o.z = excl + c.x + c.y;
    o.w = excl + c.x + c.y + c.z;
    if (base + 3 < NKEYS) *(int4*)&keyoff[base] = o;
    else {
        if (base + 0 < NKEYS) keyoff[base + 0] = o.x;
        if (base + 1 < NKEYS) keyoff[base + 1] = o.y;
        if (base + 2 < NKEYS) keyoff[base + 2] = o.z;
        if (base + 3 < NKEYS) keyoff[base + 3] = o.w;
    }
    if (tid == 255) blocksum[b] = part[255];
}

__global__ __launch_bounds__(256) void k_scanB(int* __restrict__ blocksum, int* __restrict__ blockbase,
                                               int* __restrict__ keyoff) {
    __shared__ int part[256];
    int tid = threadIdx.x;
    int v0 = (tid < SCAN_NBLK) ? blocksum[tid] : 0;
    part[tid] = v0;
    __syncthreads();
    for (int off = 1; off < 256; off <<= 1) {
        int v = (tid >= off) ? part[tid - off] : 0;
        __syncthreads();
        part[tid] += v;
        __syncthreads();
    }
    if (tid < SCAN_NBLK) blockbase[tid] = part[tid] - v0;
    if (tid == 255) keyoff[NKEYS] = part[255];
}

__global__ __launch_bounds__(256) void k_scanC(const int* __restrict__ blockbase, int* __restrict__ keyoff,
                                               int* __restrict__ cursor) {
    int b = blockIdx.x, tid = threadIdx.x;
    int base = b * SCAN_CHUNK + tid * 4;
    int add = blockbase[b];
    if (base + 3 < NKEYS) {
        int4 v = *(const int4*)&keyoff[base];
        v.x += add; v.y += add; v.z += add; v.w += add;
        *(int4*)&keyoff[base] = v;
        *(int4*)&cursor[base] = v;
    } else {
        for (int j = 0; j < 4; j++) {
            if (base + j < NKEYS) {
                int v = keyoff[base + j] + add;
                keyoff[base + j] = v;
                cursor[base + j] = v;
            }
        }
    }
}

// ---------------- scatter srcs into CSR order ----------------
__global__ __launch_bounds__(256) void k_scatter(const int* __restrict__ src, const int* __restrict__ dst,
                                                 const int* __restrict__ et, int* __restrict__ cursor,
                                                 int* __restrict__ srcs) {
    int e = blockIdx.x * blockDim.x + threadIdx.x;
    if (e < N_EDGES) {
        int p = atomicAdd(&cursor[dst[e] * 8 + et[e]], 1);
        srcs[p] = src[e];
    }
}

// ---------------- direct-fragment MFMA GEMM (qkd projections) ----------------
template <int K, int KCH, int N, int MREP, int NREP>
__global__ __launch_bounds__(256) void k_mfma_gemm(const ushort_t* __restrict__ A, const ushort_t* __restrict__ Bt,
                                                   float* __restrict__ outp, int M) {
    const int wid = threadIdx.x >> 6;
    const int lane = threadIdx.x & 63;
    const int m0 = blockIdx.x * (4 * MREP * 16) + wid * (MREP * 16);
    const int kbase = blockIdx.y * KCH;
    const int l15 = lane & 15;
    const int kq = (lane >> 4) * 8;

    f32x4 acc[MREP][NREP] = {};
    for (int kk = kbase; kk < kbase + KCH; kk += 32) {
        bf16x8 a[MREP], b[NREP];
#pragma unroll
        for (int i = 0; i < MREP; i++) {
            int row = m0 + i * 16 + l15;
            row = row < M ? row : M - 1;
            a[i] = *(const bf16x8*)&A[(size_t)row * K + kk + kq];
        }
#pragma unroll
        for (int j = 0; j < NREP; j++) b[j] = *(const bf16x8*)&Bt[(size_t)(j * 16 + l15) * K + kk + kq];
#pragma unroll
        for (int i = 0; i < MREP; i++)
#pragma unroll
            for (int j = 0; j < NREP; j++)
                acc[i][j] = __builtin_amdgcn_mfma_f32_16x16x32_bf16(a[i], b[j], acc[i][j], 0, 0, 0);
    }
    float* op = outp + (size_t)blockIdx.y * M * N;
    const int r4 = (lane >> 4) * 4;
#pragma unroll
    for (int i = 0; i < MREP; i++) {
#pragma unroll
        for (int j = 0; j < NREP; j++) {
#pragma unroll
            for (int g = 0; g < 4; g++) {
                int row = m0 + i * 16 + r4 + g;
                if (row < M) op[(size_t)row * N + j * 16 + l15] = acc[i][j][g];
            }
        }
    }
}

// ---------------- per-edge alpha from qkd (on the fly), also returns src ----------------
__device__ __forceinline__ void edge_alpha(int s_idx, const int (&ko)[9], const int* __restrict__ srcs,
                                           const float* __restrict__ qkd, const float* __restrict__ qbase,
                                           float& a0, float& a1, float& a2, int& sv) {
    int r = 0;
#pragma unroll
    for (int j = 1; j < 8; j++) r += (s_idx >= ko[j]) ? 1 : 0;
    sv = srcs[s_idx];
    const float* kd = qkd + (size_t)sv * 48 + r * 6 + 3;
    const float* qd = qbase + r * 6;
    float t0 = qd[0] + kd[0], t1 = qd[1] + kd[1], t2 = qd[2] + kd[2];
    a0 = t0 > 0.f ? t0 : NEG * t0;
    a1 = t1 > 0.f ? t1 : NEG * t1;
    a2 = t2 > 0.f ? t2 : NEG * t2;
}

// ---------------- softmax stats -> svw[e] = {src_bits, w0, w1, w2} ----------------
__global__ __launch_bounds__(256) void k_stats(const int* __restrict__ keyoff, const int* __restrict__ srcs,
                                               const float* __restrict__ qkd, float4* __restrict__ svw) {
    int node = blockIdx.x * 4 + (threadIdx.x >> 6);
    int lane = threadIdx.x & 63;
    int ko[9];
#pragma unroll
    for (int j = 0; j < 9; j++) ko[j] = keyoff[node * 8 + j];
    int beg = ko[0], end = ko[8], deg = end - beg;
    if (deg == 0) return;
    const float* qbase = qkd + (size_t)node * 48;

    if (deg <= 64) {
        float a0 = -INFINITY, a1 = -INFINITY, a2 = -INFINITY;
        int sv = 0;
        if (lane < deg) edge_alpha(beg + lane, ko, srcs, qkd, qbase, a0, a1, a2, sv);
        float m0 = a0, m1 = a1, m2 = a2;
#pragma unroll
        for (int off = 32; off >= 1; off >>= 1) {
            m0 = fmaxf(m0, __shfl_xor(m0, off));
            m1 = fmaxf(m1, __shfl_xor(m1, off));
            m2 = fmaxf(m2, __shfl_xor(m2, off));
        }
        float e0 = 0.f, e1 = 0.f, e2 = 0.f;
        if (lane < deg) {
            e0 = expf(a0 - m0);
            e1 = expf(a1 - m1);
            e2 = expf(a2 - m2);
        }
        float s0 = e0, s1 = e1, s2 = e2;
#pragma unroll
        for (int off = 32; off >= 1; off >>= 1) {
            s0 += __shfl_xor(s0, off);
            s1 += __shfl_xor(s1, off);
            s2 += __shfl_xor(s2, off);
        }
        float i0 = 1.f / (3.f * (s0 + 1e-16f));
        float i1 = 1.f / (3.f * (s1 + 1e-16f));
        float i2 = 1.f / (3.f * (s2 + 1e-16f));
        if (lane < deg)
            svw[beg + lane] = make_float4(__int_as_float(sv), e0 * i0, e1 * i1, e2 * i2);
    } else {
        float m0 = -INFINITY, m1 = -INFINITY, m2 = -INFINITY;
        for (int i = beg + lane; i < end; i += 64) {
            float a0, a1, a2; int sv;
            edge_alpha(i, ko, srcs, qkd, qbase, a0, a1, a2, sv);
            m0 = fmaxf(m0, a0); m1 = fmaxf(m1, a1); m2 = fmaxf(m2, a2);
        }
#pragma unroll
        for (int off = 32; off >= 1; off >>= 1) {
            m0 = fmaxf(m0, __shfl_xor(m0, off));
            m1 = fmaxf(m1, __shfl_xor(m1, off));
            m2 = fmaxf(m2, __shfl_xor(m2, off));
        }
        float s0 = 0.f, s1 = 0.f, s2 = 0.f;
        for (int i = beg + lane; i < end; i += 64) {
            float a0, a1, a2; int sv;
            edge_alpha(i, ko, srcs, qkd, qbase, a0, a1, a2, sv);
            s0 += expf(a0 - m0); s1 += expf(a1 - m1); s2 += expf(a2 - m2);
        }
#pragma unroll
        for (int off = 32; off >= 1; off >>= 1) {
            s0 += __shfl_xor(s0, off);
            s1 += __shfl_xor(s1, off);
            s2 += __shfl_xor(s2, off);
        }
        float i0 = 1.f / (3.f * (s0 + 1e-16f));
        float i1 = 1.f / (3.f * (s1 + 1e-16f));
        float i2 = 1.f / (3.f * (s2 + 1e-16f));
        for (int i = beg + lane; i < end; i += 64) {
            float a0, a1, a2; int sv;
            edge_alpha(i, ko, srcs, qkd, qbase, a0, a1, a2, sv);
            svw[i] = make_float4(__int_as_float(sv), expf(a0 - m0) * i0, expf(a1 - m1) * i1, expf(a2 - m2) * i2);
        }
    }
}

// ---------------- FUSED layer 1 v10: global_load_lds edge staging ----------------
// grid (1250, 8). 16 nodes/block. Per wave: up to 8 fire-and-forget staging issues
// (4 edge-rows each), one waitcnt, then accumulate from LDS.
#define PADK1 408
__global__ __launch_bounds__(256) void k_fused1(const int* __restrict__ keyoff, const int* __restrict__ srcs,
                                                const float4* __restrict__ svw, const ushort_t* __restrict__ x,
                                                const ushort_t* __restrict__ wagg, float* __restrict__ part) {
    __shared__ ushort_t stage[4][32][128];  // 32 KB: wave-private staged edge rows (linear!)
    __shared__ ushort_t lt[16][PADK1];      // 12.75 KB
    const int tid = threadIdx.x;
    const int w = tid >> 6, lane = tid & 63;
    const int q15 = lane & 15, kq = (lane >> 4) * 8;
    const int l15 = lane & 15;
    const int nbase = blockIdx.x * 16;
    const int r = blockIdx.y;
    const int ln16 = lane >> 4;          // quarter-wave id / edge-in-chunk
    const int mynode = w * 4 + ln16;
    const int key = (nbase + mynode) * 8 + r;
    const int beg = keyoff[key], end = keyoff[key + 1];
    const int deg = end - beg;

    // ---- staging: wave iterates its 4 keys, issuing global_load_lds chunks ----
#pragma unroll
    for (int qq = 0; qq < 4; qq++) {
        int kqk = (nbase + w * 4 + qq) * 8 + r;
        int b = keyoff[kqk];
        int en = keyoff[kqk + 1];
        int nst = en - b;
        nst = nst < S1ROWS ? nst : S1ROWS;
#pragma unroll
        for (int ii = 0; ii < 2; ii++) {
            if (ii * 4 < nst) {  // wave-uniform
                int jloc = ii * 4 + ln16;
                int j = b + (jloc < nst ? jloc : 0);
                int sj = srcs[j];
                gload_lds16(&x[(size_t)sj * 128 + q15 * 8], &stage[w][qq * 8 + ii * 4][0]);
            }
        }
    }
    asm volatile("s_waitcnt vmcnt(0)" ::: "memory");
    __builtin_amdgcn_sched_barrier(0);

    // ---- accumulate from LDS ----
    float a0[8] = {}, a1[8] = {}, a2[8] = {};
    const int nst = deg < S1ROWS ? deg : S1ROWS;
    for (int j = 0; j < nst; j++) {
        float4 sw = svw[beg + j];
        ushort8_t xv = *(const ushort8_t*)&stage[w][ln16 * 8 + j][q15 * 8];
#pragma unroll
        for (int c = 0; c < 8; c++) {
            float f = b2f(xv[c]);
            a0[c] += sw.y * f;
            a1[c] += sw.z * f;
            a2[c] += sw.w * f;
        }
    }
    // rare tail (deg > 8): direct global gather
    for (int s = beg + S1ROWS; s < end; s++) {
        float4 sw = svw[s];
        ushort8_t xv = *(const ushort8_t*)&x[(size_t)__float_as_int(sw.x) * 128 + q15 * 8];
#pragma unroll
        for (int c = 0; c < 8; c++) {
            float f = b2f(xv[c]);
            a0[c] += sw.y * f;
            a1[c] += sw.z * f;
            a2[c] += sw.w * f;
        }
    }
    ushort8_t o0, o1, o2;
#pragma unroll
    for (int c = 0; c < 8; c++) {
        o0[c] = f2b(a0[c]);
        o1[c] = f2b(a1[c]);
        o2[c] = f2b(a2[c]);
    }
    *(ushort8_t*)&lt[mynode][0 * 128 + q15 * 8] = o0;
    *(ushort8_t*)&lt[mynode][1 * 128 + q15 * 8] = o1;
    *(ushort8_t*)&lt[mynode][2 * 128 + q15 * 8] = o2;
    __syncthreads();

    f32x4 acc = {};
#pragma unroll
    for (int ks = 0; ks < 12; ks++) {
        bf16x8 av = *(const bf16x8*)&lt[l15][ks * 32 + kq];
        bf16x8 bv = *(const bf16x8*)&wagg[(size_t)(w * 16 + l15) * 3072 + r * 384 + ks * 32 + kq];
        acc = __builtin_amdgcn_mfma_f32_16x16x32_bf16(av, bv, acc, 0, 0, 0);
    }
    float* op = part + (size_t)r * N_NODES * 64;
    const int r4 = (lane >> 4) * 4;
#pragma unroll
    for (int g = 0; g < 4; g++) {
        int row = nbase + r4 + g;
        op[(size_t)row * 64 + w * 16 + l15] = acc[g];
    }
}

// ---------------- FUSED layer 2 v10: global_load_lds staging (128B rows) ----------------
#define PADK2 208
__global__ __launch_bounds__(256) void k_fused2(const int* __restrict__ keyoff, const int* __restrict__ srcs,
                                                const float4* __restrict__ svw, const ushort_t* __restrict__ x2in,
                                                const ushort_t* __restrict__ wagg, float* __restrict__ part) {
    __shared__ ushort_t stage[4][32][64];  // 16 KB
    __shared__ ushort_t lt[16][PADK2];     // 6.5 KB
    const int tid = threadIdx.x;
    const int w = tid >> 6, lane = tid & 63;
    const int q15 = lane & 15, kq = (lane >> 4) * 8;
    const int l15 = lane & 15;
    const int nbase = blockIdx.x * 16;
    const int r = blockIdx.y;
    const int ln16 = lane >> 4;
    const int mynode = w * 4 + ln16;
    const int key = (nbase + mynode) * 8 + r;
    const int beg = keyoff[key], end = keyoff[key + 1];
    const int deg = end - beg;

    const int e8 = lane >> 3;  // edge-in-chunk 0..7
    const int c8 = lane & 7;   // 16B chunk 0..7
#pragma unroll
    for (int qq = 0; qq < 4; qq++) {
        int kqk = (nbase + w * 4 + qq) * 8 + r;
        int b = keyoff[kqk];
        int en = keyoff[kqk + 1];
        int nst = en - b;
        nst = nst < S1ROWS ? nst : S1ROWS;
        if (nst > 0) {  // wave-uniform; one issue covers 8 edges x 128B
            int j = b + (e8 < nst ? e8 : 0);
            int sj = srcs[j];
            gload_lds16(&x2in[(size_t)sj * 64 + c8 * 8], &stage[w][qq * 8][0]);
        }
    }
    asm volatile("s_waitcnt vmcnt(0)" ::: "memory");
    __builtin_amdgcn_sched_barrier(0);

    float a0[4] = {}, a1[4] = {}, a2[4] = {};
    const int nst = deg < S1ROWS ? deg : S1ROWS;
    for (int j = 0; j < nst; j++) {
        float4 sw = svw[beg + j];
        ushort4_t xv = *(const ushort4_t*)&stage[w][ln16 * 8 + j][q15 * 4];
#pragma unroll
        for (int c = 0; c < 4; c++) {
            float f = b2f(xv[c]);
            a0[c] += sw.y * f;
            a1[c] += sw.z * f;
            a2[c] += sw.w * f;
        }
    }
    for (int s = beg + S1ROWS; s < end; s++) {
        float4 sw = svw[s];
        ushort4_t xv = *(const ushort4_t*)&x2in[(size_t)__float_as_int(sw.x) * 64 + q15 * 4];
#pragma unroll
        for (int c = 0; c < 4; c++) {
            float f = b2f(xv[c]);
            a0[c] += sw.y * f;
            a1[c] += sw.z * f;
            a2[c] += sw.w * f;
        }
    }
    ushort4_t o0, o1, o2;
#pragma unroll
    for (int c = 0; c < 4; c++) {
        o0[c] = f2b(a0[c]);
        o1[c] = f2b(a1[c]);
        o2[c] = f2b(a2[c]);
    }
    *(ushort4_t*)&lt[mynode][0 * 64 + q15 * 4] = o0;
    *(ushort4_t*)&lt[mynode][1 * 64 + q15 * 4] = o1;
    *(ushort4_t*)&lt[mynode][2 * 64 + q15 * 4] = o2;
    __syncthreads();

    if (w == 0) {
        f32x4 acc = {};
#pragma unroll
        for (int ks = 0; ks < 6; ks++) {
            bf16x8 av = *(const bf16x8*)&lt[l15][ks * 32 + kq];
            bf16x8 bv = *(const bf16x8*)&wagg[(size_t)l15 * 1536 + r * 192 + ks * 32 + kq];
            acc = __builtin_amdgcn_mfma_f32_16x16x32_bf16(av, bv, acc, 0, 0, 0);
        }
        const int r4 = (lane >> 4) * 4;
#pragma unroll
        for (int g = 0; g < 4; g++)
            part[(size_t)r * N_NODES * 16 + (size_t)(nbase + r4 + g) * 16 + l15] = acc[g];
    }
}

// ---------------- 8-way partials reduce + bias + relu -> bf16 x2 ----------------
__global__ __launch_bounds__(256) void k_reduce1(const float* __restrict__ part, const float* __restrict__ bias,
                                                 ushort_t* __restrict__ x2) {
    int idx = blockIdx.x * blockDim.x + threadIdx.x;
    const int MN = N_NODES * 64;
    if (idx >= MN) return;
    float s = bias[idx & 63];
#pragma unroll
    for (int r = 0; r < 8; r++) s += part[idx + (size_t)r * MN];
    x2[idx] = f2b(s > 0.f ? s : 0.f);
}

// ---------------- 8-way partials reduce + bias + sigmoid -> out f32 ----------------
__global__ __launch_bounds__(256) void k_reduce2(const float* __restrict__ part, const float* __restrict__ bias,
                                                 float* __restrict__ outp) {
    int idx = blockIdx.x * blockDim.x + threadIdx.x;
    const int MN = N_NODES * 16;
    if (idx >= MN) return;
    float s = bias[idx & 15];
#pragma unroll
    for (int r = 0; r < 8; r++) s += part[idx + (size_t)r * MN];
    outp[idx] = 1.f / (1.f + expf(-s));
}

extern "C" void kernel_launch(void* const* d_in, const int* in_sizes, int n_in, void* d_out, int out_size,
                              void* d_ws, size_t ws_size, hipStream_t stream) {
    const float* emb = (const float*)d_in[0];
    const float* w1 = (const float*)d_in[1];
    const float* q1 = (const float*)d_in[2];
    const float* k1 = (const float*)d_in[3];
    const float* b1 = (const float*)d_in[4];
    const float* w2 = (const float*)d_in[5];
    const float* q2 = (const float*)d_in[6];
    const float* k2 = (const float*)d_in[7];
    const float* b2 = (const float*)d_in[8];
    const int* eidx = (const int*)d_in[9];
    const int* etype = (const int*)d_in[10];
    const int* srcv = eidx;
    const int* dstv = eidx + N_EDGES;
    float* out = (float*)d_out;

    char* p = (char*)d_ws;
    auto alloc = [&](size_t bytes) -> void* {
        void* q = p;
        p += (bytes + 255) & ~(size_t)255;
        return q;
    };
    int* counts = (int*)alloc((size_t)NKEYS * 4);
    int* keyoff = (int*)alloc((size_t)(NKEYS + 1) * 4);
    int* cursor = (int*)alloc((size_t)NKEYS * 4);
    int* blocksum = (int*)alloc((size_t)SCAN_NBLK * 4);
    int* blockbase = (int*)alloc((size_t)SCAN_NBLK * 4);
    int* srcs = (int*)alloc((size_t)N_EDGES * 4);
    float4* svw = (float4*)alloc((size_t)N_EDGES * 16);
    ushort_t* emb_b = (ushort_t*)alloc((size_t)N_NODES * EMB * 2);
    ushort_t* wqkt1 = (ushort_t*)alloc((size_t)48 * 128 * 2);
    ushort_t* wagg1 = (ushort_t*)alloc((size_t)64 * 3072 * 2);
    ushort_t* wqkt2 = (ushort_t*)alloc((size_t)48 * 64 * 2);
    ushort_t* wagg2 = (ushort_t*)alloc((size_t)16 * 1536 * 2);
    float* qkd = (float*)alloc((size_t)N_NODES * 48 * 4);
    ushort_t* x2 = (ushort_t*)alloc((size_t)N_NODES * 64 * 2);
    float* partials = (float*)alloc((size_t)8 * N_NODES * 64 * 4);

    // ---- merged precomputes ----
    k_prep<<<(PREP_TOT + 255) / 256, 256, 0, stream>>>(emb, emb_b, w1, q1, k1, wqkt1, w2, q2, k2, wqkt2, wagg1,
                                                       wagg2);

    // ---- CSR over (dst, rel) ----
    hipMemsetAsync(counts, 0, (size_t)NKEYS * 4, stream);
    k_count<<<(N_EDGES + 255) / 256, 256, 0, stream>>>(dstv, etype, counts);
    k_scanA<<<SCAN_NBLK, 256, 0, stream>>>(counts, keyoff, blocksum);
    k_scanB<<<1, 256, 0, stream>>>(blocksum, blockbase, keyoff);
    k_scanC<<<SCAN_NBLK, 256, 0, stream>>>(blockbase, keyoff, cursor);
    k_scatter<<<(N_EDGES + 255) / 256, 256, 0, stream>>>(srcv, dstv, etype, cursor, srcs);

    // ---- layer 1 ----
    k_mfma_gemm<128, 128, 48, 1, 3><<<dim3(313, 1), 256, 0, stream>>>(emb_b, wqkt1, qkd, N_NODES);
    k_stats<<<N_NODES / 4, 256, 0, stream>>>(keyoff, srcs, qkd, svw);
    k_fused1<<<dim3(N_NODES / 16, 8), 256, 0, stream>>>(keyoff, srcs, svw, emb_b, wagg1, partials);
    k_reduce1<<<(N_NODES * 64 + 255) / 256, 256, 0, stream>>>(partials, b1, x2);

    // ---- layer 2 ----
    k_mfma_gemm<64, 64, 48, 1, 3><<<dim3(313, 1), 256, 0, stream>>>(x2, wqkt2, qkd, N_NODES);
    k_stats<<<N_NODES / 4, 256, 0, stream>>>(keyoff, srcs, qkd, svw);
    k_fused2<<<dim3(N_NODES / 16, 8), 256, 0, stream>>>(keyoff, srcs, svw, x2, wagg2, partials);
    k_reduce2<<<(N_NODES * 16 + 255) / 256, 256, 0, stream>>>(partials, b2, out);
}

// Round 15
// 247.200 us; speedup vs baseline: 1.2122x; 1.2122x over previous
//
#include <hip/hip_runtime.h>
#include <hip/hip_bf16.h>
#include <math.h>

#define N_NODES 20000
#define EMB 128
#define HID 64
#define RELS 8
#define CLS 16
#define N_EDGES 640000
#define NEG 0.2f
#define NKEYS (N_NODES * RELS)
#define SCAN_CHUNK 1024
#define SCAN_NBLK ((NKEYS + SCAN_CHUNK - 1) / SCAN_CHUNK)  // 157

typedef unsigned short ushort_t;
typedef __attribute__((ext_vector_type(8))) short bf16x8;
typedef __attribute__((ext_vector_type(8))) unsigned short ushort8_t;
typedef __attribute__((ext_vector_type(4))) unsigned short ushort4_t;
typedef __attribute__((ext_vector_type(4))) float f32x4;

__device__ __forceinline__ float b2f(ushort_t u) {
    return __uint_as_float(((unsigned int)u) << 16);
}
__device__ __forceinline__ ushort_t f2b(float f) {
    __hip_bfloat16 h = __float2bfloat16(f);
    return *reinterpret_cast<ushort_t*>(&h);
}

// ---------------- merged precompute: cvt + wqk1 + wqk2 + wagg1 + wagg2 ----------------
__device__ __forceinline__ void prep_cvt(int i, const float* __restrict__ in, ushort_t* __restrict__ outp) {
    float4 v = *(const float4*)&in[(size_t)i * 4];
    ushort4 o;
    o.x = f2b(v.x); o.y = f2b(v.y); o.z = f2b(v.z); o.w = f2b(v.w);
    *(ushort4*)&outp[(size_t)i * 4] = o;
}

template <int D, int OUT>
__device__ __forceinline__ void prep_wqk(int tid, const float* __restrict__ w, const float* __restrict__ q,
                                         const float* __restrict__ k, ushort_t* __restrict__ wqkt) {
    int c = tid / D, i = tid % D;
    int r = c / 6, j = c % 6;
    const float* qk = (j < 3) ? q : k;
    int jj = (j < 3) ? j : j - 3;
    const float* wrow = w + ((size_t)r * D + i) * OUT;
    float s = 0.f;
    for (int o = 0; o < OUT; o++) s += wrow[o] * qk[o * 3 + jj];
    wqkt[(size_t)c * D + i] = f2b(s);
}

template <int D, int OC>
__device__ __forceinline__ void prep_wagg(int tid, const float* __restrict__ w, ushort_t* __restrict__ outp) {
    const int KT = RELS * 3 * D;
    int kidx = tid % KT;
    int o = tid / KT;
    int r = kidx / (3 * D), h = (kidx / D) % 3, i = kidx % D;
    outp[tid] = f2b(w[((size_t)r * D + i) * (3 * OC) + h * OC + o]);
}

#define PREP_N0 (N_NODES * EMB / 4)
#define PREP_N1 (48 * 128)
#define PREP_N2 (48 * 64)
#define PREP_N3 (64 * 3072)
#define PREP_N4 (16 * 1536)
#define PREP_TOT (PREP_N0 + PREP_N1 + PREP_N2 + PREP_N3 + PREP_N4)

__global__ __launch_bounds__(256) void k_prep(const float* __restrict__ emb, ushort_t* __restrict__ emb_b,
                                              const float* __restrict__ w1, const float* __restrict__ q1,
                                              const float* __restrict__ k1, ushort_t* __restrict__ wqkt1,
                                              const float* __restrict__ w2, const float* __restrict__ q2,
                                              const float* __restrict__ k2, ushort_t* __restrict__ wqkt2,
                                              ushort_t* __restrict__ wagg1, ushort_t* __restrict__ wagg2) {
    int tid = blockIdx.x * 256 + threadIdx.x;
    if (tid < PREP_N0) { prep_cvt(tid, emb, emb_b); return; }
    tid -= PREP_N0;
    if (tid < PREP_N1) { prep_wqk<128, 192>(tid, w1, q1, k1, wqkt1); return; }
    tid -= PREP_N1;
    if (tid < PREP_N2) { prep_wqk<64, 48>(tid, w2, q2, k2, wqkt2); return; }
    tid -= PREP_N2;
    if (tid < PREP_N3) { prep_wagg<128, 64>(tid, w1, wagg1); return; }
    tid -= PREP_N3;
    if (tid < PREP_N4) { prep_wagg<64, 16>(tid, w2, wagg2); return; }
}

// ---------------- CSR build over keys = dst*8 + rel ----------------
__global__ __launch_bounds__(256) void k_count(const int* __restrict__ dst, const int* __restrict__ et,
                                               int* __restrict__ counts) {
    int e = blockIdx.x * blockDim.x + threadIdx.x;
    if (e < N_EDGES) atomicAdd(&counts[dst[e] * 8 + et[e]], 1);
}

__global__ __launch_bounds__(256) void k_scanA(const int* __restrict__ counts, int* __restrict__ keyoff,
                                               int* __restrict__ blocksum) {
    __shared__ int part[256];
    int b = blockIdx.x, tid = threadIdx.x;
    int base = b * SCAN_CHUNK + tid * 4;
    int4 c = make_int4(0, 0, 0, 0);
    if (base + 3 < NKEYS) c = *(const int4*)&counts[base];
    else {
        if (base + 0 < NKEYS) c.x = counts[base + 0];
        if (base + 1 < NKEYS) c.y = counts[base + 1];
        if (base + 2 < NKEYS) c.z = counts[base + 2];
        if (base + 3 < NKEYS) c.w = counts[base + 3];
    }
    int s = c.x + c.y + c.z + c.w;
    part[tid] = s;
    __syncthreads();
    for (int off = 1; off < 256; off <<= 1) {
        int v = (tid >= off) ? part[tid - off] : 0;
        __syncthreads();
        part[tid] += v;
        __syncthreads();
    }
    int excl = part[tid] - s;
    int4 o;
    o.x = excl;
    o.y = excl + c.x;
    o.z = excl + c.x + c.y;
    o.w = excl + c.x + c.y + c.z;
    if (base + 3 < NKEYS) *(int4*)&keyoff[base] = o;
    else {
        if (base + 0 < NKEYS) keyoff[base + 0] = o.x;
        if (base + 1 < NKEYS) keyoff[base + 1] = o.y;
        if (base + 2 < NKEYS) keyoff[base + 2] = o.z;
        if (base + 3 < NKEYS) keyoff[base + 3] = o.w;
    }
    if (tid == 255) blocksum[b] = part[255];
}

__global__ __launch_bounds__(256) void k_scanB(int* __restrict__ blocksum, int* __restrict__ blockbase,
                                               int* __restrict__ keyoff) {
    __shared__ int part[256];
    int tid = threadIdx.x;
    int v0 = (tid < SCAN_NBLK) ? blocksum[tid] : 0;
    part[tid] = v0;
    __syncthreads();
    for (int off = 1; off < 256; off <<= 1) {
        int v = (tid >= off) ? part[tid - off] : 0;
        __syncthreads();
        part[tid] += v;
        __syncthreads();
    }
    if (tid < SCAN_NBLK) blockbase[tid] = part[tid] - v0;
    if (tid == 255) keyoff[NKEYS] = part[255];
}

__global__ __launch_bounds__(256) void k_scanC(const int* __restrict__ blockbase, int* __restrict__ keyoff,
                                               int* __restrict__ cursor) {
    int b = blockIdx.x, tid = threadIdx.x;
    int base = b * SCAN_CHUNK + tid * 4;
    int add = blockbase[b];
    if (base + 3 < NKEYS) {
        int4 v = *(const int4*)&keyoff[base];
        v.x += add; v.y += add; v.z += add; v.w += add;
        *(int4*)&keyoff[base] = v;
        *(int4*)&cursor[base] = v;
    } else {
        for (int j = 0; j < 4; j++) {
            if (base + j < NKEYS) {
                int v = keyoff[base + j] + add;
                keyoff[base + j] = v;
                cursor[base + j] = v;
            }
        }
    }
}

// ---------------- scatter srcs into CSR order ----------------
__global__ __launch_bounds__(256) void k_scatter(const int* __restrict__ src, const int* __restrict__ dst,
                                                 const int* __restrict__ et, int* __restrict__ cursor,
                                                 int* __restrict__ srcs) {
    int e = blockIdx.x * blockDim.x + threadIdx.x;
    if (e < N_EDGES) {
        int p = atomicAdd(&cursor[dst[e] * 8 + et[e]], 1);
        srcs[p] = src[e];
    }
}

// ---------------- direct-fragment MFMA GEMM (qkd projections) ----------------
template <int K, int KCH, int N, int MREP, int NREP>
__global__ __launch_bounds__(256) void k_mfma_gemm(const ushort_t* __restrict__ A, const ushort_t* __restrict__ Bt,
                                                   float* __restrict__ outp, int M) {
    const int wid = threadIdx.x >> 6;
    const int lane = threadIdx.x & 63;
    const int m0 = blockIdx.x * (4 * MREP * 16) + wid * (MREP * 16);
    const int kbase = blockIdx.y * KCH;
    const int l15 = lane & 15;
    const int kq = (lane >> 4) * 8;

    f32x4 acc[MREP][NREP] = {};
    for (int kk = kbase; kk < kbase + KCH; kk += 32) {
        bf16x8 a[MREP], b[NREP];
#pragma unroll
        for (int i = 0; i < MREP; i++) {
            int row = m0 + i * 16 + l15;
            row = row < M ? row : M - 1;
            a[i] = *(const bf16x8*)&A[(size_t)row * K + kk + kq];
        }
#pragma unroll
        for (int j = 0; j < NREP; j++) b[j] = *(const bf16x8*)&Bt[(size_t)(j * 16 + l15) * K + kk + kq];
#pragma unroll
        for (int i = 0; i < MREP; i++)
#pragma unroll
            for (int j = 0; j < NREP; j++)
                acc[i][j] = __builtin_amdgcn_mfma_f32_16x16x32_bf16(a[i], b[j], acc[i][j], 0, 0, 0);
    }
    float* op = outp + (size_t)blockIdx.y * M * N;
    const int r4 = (lane >> 4) * 4;
#pragma unroll
    for (int i = 0; i < MREP; i++) {
#pragma unroll
        for (int j = 0; j < NREP; j++) {
#pragma unroll
            for (int g = 0; g < 4; g++) {
                int row = m0 + i * 16 + r4 + g;
                if (row < M) op[(size_t)row * N + j * 16 + l15] = acc[i][j][g];
            }
        }
    }
}

// ---------------- per-edge alpha from qkd (on the fly), also returns src ----------------
__device__ __forceinline__ void edge_alpha(int s_idx, const int (&ko)[9], const int* __restrict__ srcs,
                                           const float* __restrict__ qkd, const float* __restrict__ qbase,
                                           float& a0, float& a1, float& a2, int& sv) {
    int r = 0;
#pragma unroll
    for (int j = 1; j < 8; j++) r += (s_idx >= ko[j]) ? 1 : 0;
    sv = srcs[s_idx];
    const float* kd = qkd + (size_t)sv * 48 + r * 6 + 3;
    const float* qd = qbase + r * 6;
    float t0 = qd[0] + kd[0], t1 = qd[1] + kd[1], t2 = qd[2] + kd[2];
    a0 = t0 > 0.f ? t0 : NEG * t0;
    a1 = t1 > 0.f ? t1 : NEG * t1;
    a2 = t2 > 0.f ? t2 : NEG * t2;
}

// ---------------- softmax stats -> svw[e] = {src_bits, w0, w1, w2} ----------------
__global__ __launch_bounds__(256) void k_stats(const int* __restrict__ keyoff, const int* __restrict__ srcs,
                                               const float* __restrict__ qkd, float4* __restrict__ svw) {
    int node = blockIdx.x * 4 + (threadIdx.x >> 6);
    int lane = threadIdx.x & 63;
    int ko[9];
#pragma unroll
    for (int j = 0; j < 9; j++) ko[j] = keyoff[node * 8 + j];
    int beg = ko[0], end = ko[8], deg = end - beg;
    if (deg == 0) return;
    const float* qbase = qkd + (size_t)node * 48;

    if (deg <= 64) {
        float a0 = -INFINITY, a1 = -INFINITY, a2 = -INFINITY;
        int sv = 0;
        if (lane < deg) edge_alpha(beg + lane, ko, srcs, qkd, qbase, a0, a1, a2, sv);
        float m0 = a0, m1 = a1, m2 = a2;
#pragma unroll
        for (int off = 32; off >= 1; off >>= 1) {
            m0 = fmaxf(m0, __shfl_xor(m0, off));
            m1 = fmaxf(m1, __shfl_xor(m1, off));
            m2 = fmaxf(m2, __shfl_xor(m2, off));
        }
        float e0 = 0.f, e1 = 0.f, e2 = 0.f;
        if (lane < deg) {
            e0 = expf(a0 - m0);
            e1 = expf(a1 - m1);
            e2 = expf(a2 - m2);
        }
        float s0 = e0, s1 = e1, s2 = e2;
#pragma unroll
        for (int off = 32; off >= 1; off >>= 1) {
            s0 += __shfl_xor(s0, off);
            s1 += __shfl_xor(s1, off);
            s2 += __shfl_xor(s2, off);
        }
        float i0 = 1.f / (3.f * (s0 + 1e-16f));
        float i1 = 1.f / (3.f * (s1 + 1e-16f));
        float i2 = 1.f / (3.f * (s2 + 1e-16f));
        if (lane < deg)
            svw[beg + lane] = make_float4(__int_as_float(sv), e0 * i0, e1 * i1, e2 * i2);
    } else {
        float m0 = -INFINITY, m1 = -INFINITY, m2 = -INFINITY;
        for (int i = beg + lane; i < end; i += 64) {
            float a0, a1, a2; int sv;
            edge_alpha(i, ko, srcs, qkd, qbase, a0, a1, a2, sv);
            m0 = fmaxf(m0, a0); m1 = fmaxf(m1, a1); m2 = fmaxf(m2, a2);
        }
#pragma unroll
        for (int off = 32; off >= 1; off >>= 1) {
            m0 = fmaxf(m0, __shfl_xor(m0, off));
            m1 = fmaxf(m1, __shfl_xor(m1, off));
            m2 = fmaxf(m2, __shfl_xor(m2, off));
        }
        float s0 = 0.f, s1 = 0.f, s2 = 0.f;
        for (int i = beg + lane; i < end; i += 64) {
            float a0, a1, a2; int sv;
            edge_alpha(i, ko, srcs, qkd, qbase, a0, a1, a2, sv);
            s0 += expf(a0 - m0); s1 += expf(a1 - m1); s2 += expf(a2 - m2);
        }
#pragma unroll
        for (int off = 32; off >= 1; off >>= 1) {
            s0 += __shfl_xor(s0, off);
            s1 += __shfl_xor(s1, off);
            s2 += __shfl_xor(s2, off);
        }
        float i0 = 1.f / (3.f * (s0 + 1e-16f));
        float i1 = 1.f / (3.f * (s1 + 1e-16f));
        float i2 = 1.f / (3.f * (s2 + 1e-16f));
        for (int i = beg + lane; i < end; i += 64) {
            float a0, a1, a2; int sv;
            edge_alpha(i, ko, srcs, qkd, qbase, a0, a1, a2, sv);
            svw[i] = make_float4(__int_as_float(sv), expf(a0 - m0) * i0, expf(a1 - m1) * i1, expf(a2 - m2) * i2);
        }
    }
}

// ---------------- FUSED layer 1 v11: parity-split gather (8 waves), dual-tile MFMA ----------------
// grid (1250, 8), 512 threads. Waves 0-3: even edges; waves 4-7: odd edges.
// Each parity accumulates its partial tile lt[p]; MFMA sums both (f32 accumulate).
#define PADK1 408
__global__ __launch_bounds__(512) void k_fused1(const int* __restrict__ keyoff, const float4* __restrict__ svw,
                                                const ushort_t* __restrict__ x, const ushort_t* __restrict__ wagg,
                                                float* __restrict__ part) {
    __shared__ ushort_t lt[2][16][PADK1];  // 25.5 KB
    const int tid = threadIdx.x;
    const int w = tid >> 6, lane = tid & 63;
    const int q15 = lane & 15, kq = (lane >> 4) * 8;
    const int l15 = lane & 15;
    const int nbase = blockIdx.x * 16;
    const int r = blockIdx.y;
    const int mynode = (w & 3) * 4 + (lane >> 4);
    const int p = w >> 2;  // parity
    const int key = (nbase + mynode) * 8 + r;

    const int beg = keyoff[key], end = keyoff[key + 1];
    float a0[8] = {}, a1[8] = {}, a2[8] = {};
    {
        int sA = beg + p;
        if (sA < end) {
            float4 sw0 = svw[sA];
            int sB = sA + 2;
            float4 sw1 = svw[sB < end ? sB : beg];
            if (sB >= end) { sw1.y = 0.f; sw1.z = 0.f; sw1.w = 0.f; }
            ushort8_t xv0 = *(const ushort8_t*)&x[(size_t)__float_as_int(sw0.x) * 128 + q15 * 8];
            for (int s = sA; s < end; s += 2) {
                int sC = s + 4;
                float4 sw2 = svw[sC < end ? sC : beg];
                if (sC >= end) { sw2.y = 0.f; sw2.z = 0.f; sw2.w = 0.f; }
                ushort8_t xv1 = *(const ushort8_t*)&x[(size_t)__float_as_int(sw1.x) * 128 + q15 * 8];
#pragma unroll
                for (int c = 0; c < 8; c++) {
                    float f = b2f(xv0[c]);
                    a0[c] += sw0.y * f;
                    a1[c] += sw0.z * f;
                    a2[c] += sw0.w * f;
                }
                sw0 = sw1;
                sw1 = sw2;
                xv0 = xv1;
            }
        }
    }
    ushort8_t o0, o1, o2;
#pragma unroll
    for (int c = 0; c < 8; c++) {
        o0[c] = f2b(a0[c]);
        o1[c] = f2b(a1[c]);
        o2[c] = f2b(a2[c]);
    }
    *(ushort8_t*)&lt[p][mynode][0 * 128 + q15 * 8] = o0;
    *(ushort8_t*)&lt[p][mynode][1 * 128 + q15 * 8] = o1;
    *(ushort8_t*)&lt[p][mynode][2 * 128 + q15 * 8] = o2;
    __syncthreads();

    if (w < 4) {
        f32x4 acc = {};
#pragma unroll
        for (int ks = 0; ks < 12; ks++) {
            bf16x8 bv = *(const bf16x8*)&wagg[(size_t)(w * 16 + l15) * 3072 + r * 384 + ks * 32 + kq];
            bf16x8 av0 = *(const bf16x8*)&lt[0][l15][ks * 32 + kq];
            bf16x8 av1 = *(const bf16x8*)&lt[1][l15][ks * 32 + kq];
            acc = __builtin_amdgcn_mfma_f32_16x16x32_bf16(av0, bv, acc, 0, 0, 0);
            acc = __builtin_amdgcn_mfma_f32_16x16x32_bf16(av1, bv, acc, 0, 0, 0);
        }
        float* op = part + (size_t)r * N_NODES * 64;
        const int r4 = (lane >> 4) * 4;
#pragma unroll
        for (int g = 0; g < 4; g++) {
            int row = nbase + r4 + g;
            op[(size_t)row * 64 + w * 16 + l15] = acc[g];
        }
    }
}

// ---------------- FUSED layer 2 v8 (R12): one rel per block + pipelined gather ----------------
#define PADK2 208
__global__ __launch_bounds__(256) void k_fused2(const int* __restrict__ keyoff, const float4* __restrict__ svw,
                                                const ushort_t* __restrict__ x2in, const ushort_t* __restrict__ wagg,
                                                float* __restrict__ part) {
    __shared__ ushort_t lt[16][PADK2];  // 6.5 KB
    const int tid = threadIdx.x;
    const int w = tid >> 6, lane = tid & 63;
    const int q15 = lane & 15, kq = (lane >> 4) * 8;
    const int l15 = lane & 15;
    const int nbase = blockIdx.x * 16;
    const int r = blockIdx.y;
    const int mynode = w * 4 + (lane >> 4);
    const int key = (nbase + mynode) * 8 + r;

    const int beg = keyoff[key], end = keyoff[key + 1];
    const int deg = end - beg;
    float a0[4] = {}, a1[4] = {}, a2[4] = {};
    if (deg > 0) {
        float4 sw0 = svw[beg];
        float4 sw1;
        {
            int s = beg + 1;
            sw1 = svw[s < end ? s : beg];
            if (1 >= deg) { sw1.y = 0.f; sw1.z = 0.f; sw1.w = 0.f; }
        }
        ushort4_t xv0 = *(const ushort4_t*)&x2in[(size_t)__float_as_int(sw0.x) * 64 + q15 * 4];
        for (int i = 0; i < deg; i++) {
            float4 sw2;
            {
                int s = beg + i + 2;
                sw2 = svw[s < end ? s : beg];
                if (i + 2 >= deg) { sw2.y = 0.f; sw2.z = 0.f; sw2.w = 0.f; }
            }
            ushort4_t xv1 = *(const ushort4_t*)&x2in[(size_t)__float_as_int(sw1.x) * 64 + q15 * 4];
#pragma unroll
            for (int c = 0; c < 4; c++) {
                float f = b2f(xv0[c]);
                a0[c] += sw0.y * f;
                a1[c] += sw0.z * f;
                a2[c] += sw0.w * f;
            }
            sw0 = sw1;
            sw1 = sw2;
            xv0 = xv1;
        }
    }
    ushort4_t o0, o1, o2;
#pragma unroll
    for (int c = 0; c < 4; c++) {
        o0[c] = f2b(a0[c]);
        o1[c] = f2b(a1[c]);
        o2[c] = f2b(a2[c]);
    }
    *(ushort4_t*)&lt[mynode][0 * 64 + q15 * 4] = o0;
    *(ushort4_t*)&lt[mynode][1 * 64 + q15 * 4] = o1;
    *(ushort4_t*)&lt[mynode][2 * 64 + q15 * 4] = o2;
    __syncthreads();

    if (w == 0) {
        f32x4 acc = {};
#pragma unroll
        for (int ks = 0; ks < 6; ks++) {
            bf16x8 av = *(const bf16x8*)&lt[l15][ks * 32 + kq];
            bf16x8 bv = *(const bf16x8*)&wagg[(size_t)l15 * 1536 + r * 192 + ks * 32 + kq];
            acc = __builtin_amdgcn_mfma_f32_16x16x32_bf16(av, bv, acc, 0, 0, 0);
        }
        const int r4 = (lane >> 4) * 4;
#pragma unroll
        for (int g = 0; g < 4; g++)
            part[(size_t)r * N_NODES * 16 + (size_t)(nbase + r4 + g) * 16 + l15] = acc[g];
    }
}

// ---------------- 8-way partials reduce + bias + relu -> bf16 x2 ----------------
__global__ __launch_bounds__(256) void k_reduce1(const float* __restrict__ part, const float* __restrict__ bias,
                                                 ushort_t* __restrict__ x2) {
    int idx = blockIdx.x * blockDim.x + threadIdx.x;
    const int MN = N_NODES * 64;
    if (idx >= MN) return;
    float s = bias[idx & 63];
#pragma unroll
    for (int r = 0; r < 8; r++) s += part[idx + (size_t)r * MN];
    x2[idx] = f2b(s > 0.f ? s : 0.f);
}

// ---------------- 8-way partials reduce + bias + sigmoid -> out f32 ----------------
__global__ __launch_bounds__(256) void k_reduce2(const float* __restrict__ part, const float* __restrict__ bias,
                                                 float* __restrict__ outp) {
    int idx = blockIdx.x * blockDim.x + threadIdx.x;
    const int MN = N_NODES * 16;
    if (idx >= MN) return;
    float s = bias[idx & 15];
#pragma unroll
    for (int r = 0; r < 8; r++) s += part[idx + (size_t)r * MN];
    outp[idx] = 1.f / (1.f + expf(-s));
}

extern "C" void kernel_launch(void* const* d_in, const int* in_sizes, int n_in, void* d_out, int out_size,
                              void* d_ws, size_t ws_size, hipStream_t stream) {
    const float* emb = (const float*)d_in[0];
    const float* w1 = (const float*)d_in[1];
    const float* q1 = (const float*)d_in[2];
    const float* k1 = (const float*)d_in[3];
    const float* b1 = (const float*)d_in[4];
    const float* w2 = (const float*)d_in[5];
    const float* q2 = (const float*)d_in[6];
    const float* k2 = (const float*)d_in[7];
    const float* b2 = (const float*)d_in[8];
    const int* eidx = (const int*)d_in[9];
    const int* etype = (const int*)d_in[10];
    const int* srcv = eidx;
    const int* dstv = eidx + N_EDGES;
    float* out = (float*)d_out;

    char* p = (char*)d_ws;
    auto alloc = [&](size_t bytes) -> void* {
        void* q = p;
        p += (bytes + 255) & ~(size_t)255;
        return q;
    };
    int* counts = (int*)alloc((size_t)NKEYS * 4);
    int* keyoff = (int*)alloc((size_t)(NKEYS + 1) * 4);
    int* cursor = (int*)alloc((size_t)NKEYS * 4);
    int* blocksum = (int*)alloc((size_t)SCAN_NBLK * 4);
    int* blockbase = (int*)alloc((size_t)SCAN_NBLK * 4);
    int* srcs = (int*)alloc((size_t)N_EDGES * 4);
    float4* svw = (float4*)alloc((size_t)N_EDGES * 16);
    ushort_t* emb_b = (ushort_t*)alloc((size_t)N_NODES * EMB * 2);
    ushort_t* wqkt1 = (ushort_t*)alloc((size_t)48 * 128 * 2);
    ushort_t* wagg1 = (ushort_t*)alloc((size_t)64 * 3072 * 2);
    ushort_t* wqkt2 = (ushort_t*)alloc((size_t)48 * 64 * 2);
    ushort_t* wagg2 = (ushort_t*)alloc((size_t)16 * 1536 * 2);
    float* qkd = (float*)alloc((size_t)N_NODES * 48 * 4);
    ushort_t* x2 = (ushort_t*)alloc((size_t)N_NODES * 64 * 2);
    float* partials = (float*)alloc((size_t)8 * N_NODES * 64 * 4);

    // ---- merged precomputes ----
    k_prep<<<(PREP_TOT + 255) / 256, 256, 0, stream>>>(emb, emb_b, w1, q1, k1, wqkt1, w2, q2, k2, wqkt2, wagg1,
                                                       wagg2);

    // ---- CSR over (dst, rel) ----
    hipMemsetAsync(counts, 0, (size_t)NKEYS * 4, stream);
    k_count<<<(N_EDGES + 255) / 256, 256, 0, stream>>>(dstv, etype, counts);
    k_scanA<<<SCAN_NBLK, 256, 0, stream>>>(counts, keyoff, blocksum);
    k_scanB<<<1, 256, 0, stream>>>(blocksum, blockbase, keyoff);
    k_scanC<<<SCAN_NBLK, 256, 0, stream>>>(blockbase, keyoff, cursor);
    k_scatter<<<(N_EDGES + 255) / 256, 256, 0, stream>>>(srcv, dstv, etype, cursor, srcs);

    // ---- layer 1 ----
    k_mfma_gemm<128, 128, 48, 1, 3><<<dim3(313, 1), 256, 0, stream>>>(emb_b, wqkt1, qkd, N_NODES);
    k_stats<<<N_NODES / 4, 256, 0, stream>>>(keyoff, srcs, qkd, svw);
    k_fused1<<<dim3(N_NODES / 16, 8), 512, 0, stream>>>(keyoff, svw, emb_b, wagg1, partials);
    k_reduce1<<<(N_NODES * 64 + 255) / 256, 256, 0, stream>>>(partials, b1, x2);

    // ---- layer 2 ----
    k_mfma_gemm<64, 64, 48, 1, 3><<<dim3(313, 1), 256, 0, stream>>>(x2, wqkt2, qkd, N_NODES);
    k_stats<<<N_NODES / 4, 256, 0, stream>>>(keyoff, srcs, qkd, svw);
    k_fused2<<<dim3(N_NODES / 16, 8), 256, 0, stream>>>(keyoff, svw, x2, wagg2, partials);
    k_reduce2<<<(N_NODES * 16 + 255) / 256, 256, 0, stream>>>(partials, b2, out);
}

// Round 16
// 244.828 us; speedup vs baseline: 1.2240x; 1.0097x over previous
//
#include <hip/hip_runtime.h>
#include <hip/hip_bf16.h>
#include <math.h>

#define N_NODES 20000
#define EMB 128
#define HID 64
#define RELS 8
#define CLS 16
#define N_EDGES 640000
#define NEG 0.2f
#define NKEYS (N_NODES * RELS)
#define SCAN_CHUNK 1024
#define SCAN_NBLK ((NKEYS + SCAN_CHUNK - 1) / SCAN_CHUNK)  // 157

typedef unsigned short ushort_t;
typedef __attribute__((ext_vector_type(8))) short bf16x8;
typedef __attribute__((ext_vector_type(8))) unsigned short ushort8_t;
typedef __attribute__((ext_vector_type(4))) unsigned short ushort4_t;
typedef __attribute__((ext_vector_type(4))) float f32x4;

__device__ __forceinline__ float b2f(ushort_t u) {
    return __uint_as_float(((unsigned int)u) << 16);
}
__device__ __forceinline__ ushort_t f2b(float f) {
    __hip_bfloat16 h = __float2bfloat16(f);
    return *reinterpret_cast<ushort_t*>(&h);
}

// ---------------- merged precompute: cvt + wqk1 + wqk2 + wagg1 + wagg2 ----------------
__device__ __forceinline__ void prep_cvt(int i, const float* __restrict__ in, ushort_t* __restrict__ outp) {
    float4 v = *(const float4*)&in[(size_t)i * 4];
    ushort4 o;
    o.x = f2b(v.x); o.y = f2b(v.y); o.z = f2b(v.z); o.w = f2b(v.w);
    *(ushort4*)&outp[(size_t)i * 4] = o;
}

template <int D, int OUT>
__device__ __forceinline__ void prep_wqk(int tid, const float* __restrict__ w, const float* __restrict__ q,
                                         const float* __restrict__ k, ushort_t* __restrict__ wqkt) {
    int c = tid / D, i = tid % D;
    int r = c / 6, j = c % 6;
    const float* qk = (j < 3) ? q : k;
    int jj = (j < 3) ? j : j - 3;
    const float* wrow = w + ((size_t)r * D + i) * OUT;
    float s = 0.f;
    for (int o = 0; o < OUT; o++) s += wrow[o] * qk[o * 3 + jj];
    wqkt[(size_t)c * D + i] = f2b(s);
}

template <int D, int OC>
__device__ __forceinline__ void prep_wagg(int tid, const float* __restrict__ w, ushort_t* __restrict__ outp) {
    const int KT = RELS * 3 * D;
    int kidx = tid % KT;
    int o = tid / KT;
    int r = kidx / (3 * D), h = (kidx / D) % 3, i = kidx % D;
    outp[tid] = f2b(w[((size_t)r * D + i) * (3 * OC) + h * OC + o]);
}

#define PREP_N0 (N_NODES * EMB / 4)
#define PREP_N1 (48 * 128)
#define PREP_N2 (48 * 64)
#define PREP_N3 (64 * 3072)
#define PREP_N4 (16 * 1536)
#define PREP_TOT (PREP_N0 + PREP_N1 + PREP_N2 + PREP_N3 + PREP_N4)

__global__ __launch_bounds__(256) void k_prep(const float* __restrict__ emb, ushort_t* __restrict__ emb_b,
                                              const float* __restrict__ w1, const float* __restrict__ q1,
                                              const float* __restrict__ k1, ushort_t* __restrict__ wqkt1,
                                              const float* __restrict__ w2, const float* __restrict__ q2,
                                              const float* __restrict__ k2, ushort_t* __restrict__ wqkt2,
                                              ushort_t* __restrict__ wagg1, ushort_t* __restrict__ wagg2) {
    int tid = blockIdx.x * 256 + threadIdx.x;
    if (tid < PREP_N0) { prep_cvt(tid, emb, emb_b); return; }
    tid -= PREP_N0;
    if (tid < PREP_N1) { prep_wqk<128, 192>(tid, w1, q1, k1, wqkt1); return; }
    tid -= PREP_N1;
    if (tid < PREP_N2) { prep_wqk<64, 48>(tid, w2, q2, k2, wqkt2); return; }
    tid -= PREP_N2;
    if (tid < PREP_N3) { prep_wagg<128, 64>(tid, w1, wagg1); return; }
    tid -= PREP_N3;
    if (tid < PREP_N4) { prep_wagg<64, 16>(tid, w2, wagg2); return; }
}

// ---------------- CSR build over keys = dst*8 + rel ----------------
__global__ __launch_bounds__(256) void k_count(const int* __restrict__ dst, const int* __restrict__ et,
                                               int* __restrict__ counts) {
    int e = blockIdx.x * blockDim.x + threadIdx.x;
    if (e < N_EDGES) atomicAdd(&counts[dst[e] * 8 + et[e]], 1);
}

__global__ __launch_bounds__(256) void k_scanA(const int* __restrict__ counts, int* __restrict__ keyoff,
                                               int* __restrict__ blocksum) {
    __shared__ int part[256];
    int b = blockIdx.x, tid = threadIdx.x;
    int base = b * SCAN_CHUNK + tid * 4;
    int4 c = make_int4(0, 0, 0, 0);
    if (base + 3 < NKEYS) c = *(const int4*)&counts[base];
    else {
        if (base + 0 < NKEYS) c.x = counts[base + 0];
        if (base + 1 < NKEYS) c.y = counts[base + 1];
        if (base + 2 < NKEYS) c.z = counts[base + 2];
        if (base + 3 < NKEYS) c.w = counts[base + 3];
    }
    int s = c.x + c.y + c.z + c.w;
    part[tid] = s;
    __syncthreads();
    for (int off = 1; off < 256; off <<= 1) {
        int v = (tid >= off) ? part[tid - off] : 0;
        __syncthreads();
        part[tid] += v;
        __syncthreads();
    }
    int excl = part[tid] - s;
    int4 o;
    o.x = excl;
    o.y = excl + c.x;
    o.z = excl + c.x + c.y;
    o.w = excl + c.x + c.y + c.z;
    if (base + 3 < NKEYS) *(int4*)&keyoff[base] = o;
    else {
        if (base + 0 < NKEYS) keyoff[base + 0] = o.x;
        if (base + 1 < NKEYS) keyoff[base + 1] = o.y;
        if (base + 2 < NKEYS) keyoff[base + 2] = o.z;
        if (base + 3 < NKEYS) keyoff[base + 3] = o.w;
    }
    if (tid == 255) blocksum[b] = part[255];
}

__global__ __launch_bounds__(256) void k_scanB(int* __restrict__ blocksum, int* __restrict__ blockbase,
                                               int* __restrict__ keyoff) {
    __shared__ int part[256];
    int tid = threadIdx.x;
    int v0 = (tid < SCAN_NBLK) ? blocksum[tid] : 0;
    part[tid] = v0;
    __syncthreads();
    for (int off = 1; off < 256; off <<= 1) {
        int v = (tid >= off) ? part[tid - off] : 0;
        __syncthreads();
        part[tid] += v;
        __syncthreads();
    }
    if (tid < SCAN_NBLK) blockbase[tid] = part[tid] - v0;
    if (tid == 255) keyoff[NKEYS] = part[255];
}

__global__ __launch_bounds__(256) void k_scanC(const int* __restrict__ blockbase, int* __restrict__ keyoff,
                                               int* __restrict__ cursor) {
    int b = blockIdx.x, tid = threadIdx.x;
    int base = b * SCAN_CHUNK + tid * 4;
    int add = blockbase[b];
    if (base + 3 < NKEYS) {
        int4 v = *(const int4*)&keyoff[base];
        v.x += add; v.y += add; v.z += add; v.w += add;
        *(int4*)&keyoff[base] = v;
        *(int4*)&cursor[base] = v;
    } else {
        for (int j = 0; j < 4; j++) {
            if (base + j < NKEYS) {
                int v = keyoff[base + j] + add;
                keyoff[base + j] = v;
                cursor[base + j] = v;
            }
        }
    }
}

// ---------------- scatter srcs into CSR order ----------------
__global__ __launch_bounds__(256) void k_scatter(const int* __restrict__ src, const int* __restrict__ dst,
                                                 const int* __restrict__ et, int* __restrict__ cursor,
                                                 int* __restrict__ srcs) {
    int e = blockIdx.x * blockDim.x + threadIdx.x;
    if (e < N_EDGES) {
        int p = atomicAdd(&cursor[dst[e] * 8 + et[e]], 1);
        srcs[p] = src[e];
    }
}

// ---------------- direct-fragment MFMA GEMM (qkd projections) ----------------
template <int K, int KCH, int N, int MREP, int NREP>
__global__ __launch_bounds__(256) void k_mfma_gemm(const ushort_t* __restrict__ A, const ushort_t* __restrict__ Bt,
                                                   float* __restrict__ outp, int M) {
    const int wid = threadIdx.x >> 6;
    const int lane = threadIdx.x & 63;
    const int m0 = blockIdx.x * (4 * MREP * 16) + wid * (MREP * 16);
    const int kbase = blockIdx.y * KCH;
    const int l15 = lane & 15;
    const int kq = (lane >> 4) * 8;

    f32x4 acc[MREP][NREP] = {};
    for (int kk = kbase; kk < kbase + KCH; kk += 32) {
        bf16x8 a[MREP], b[NREP];
#pragma unroll
        for (int i = 0; i < MREP; i++) {
            int row = m0 + i * 16 + l15;
            row = row < M ? row : M - 1;
            a[i] = *(const bf16x8*)&A[(size_t)row * K + kk + kq];
        }
#pragma unroll
        for (int j = 0; j < NREP; j++) b[j] = *(const bf16x8*)&Bt[(size_t)(j * 16 + l15) * K + kk + kq];
#pragma unroll
        for (int i = 0; i < MREP; i++)
#pragma unroll
            for (int j = 0; j < NREP; j++)
                acc[i][j] = __builtin_amdgcn_mfma_f32_16x16x32_bf16(a[i], b[j], acc[i][j], 0, 0, 0);
    }
    float* op = outp + (size_t)blockIdx.y * M * N;
    const int r4 = (lane >> 4) * 4;
#pragma unroll
    for (int i = 0; i < MREP; i++) {
#pragma unroll
        for (int j = 0; j < NREP; j++) {
#pragma unroll
            for (int g = 0; g < 4; g++) {
                int row = m0 + i * 16 + r4 + g;
                if (row < M) op[(size_t)row * N + j * 16 + l15] = acc[i][j][g];
            }
        }
    }
}

// ---------------- per-edge alpha from qkd (on the fly), also returns src ----------------
__device__ __forceinline__ void edge_alpha(int s_idx, const int (&ko)[9], const int* __restrict__ srcs,
                                           const float* __restrict__ qkd, const float* __restrict__ qbase,
                                           float& a0, float& a1, float& a2, int& sv) {
    int r = 0;
#pragma unroll
    for (int j = 1; j < 8; j++) r += (s_idx >= ko[j]) ? 1 : 0;
    sv = srcs[s_idx];
    const float* kd = qkd + (size_t)sv * 48 + r * 6 + 3;
    const float* qd = qbase + r * 6;
    float t0 = qd[0] + kd[0], t1 = qd[1] + kd[1], t2 = qd[2] + kd[2];
    a0 = t0 > 0.f ? t0 : NEG * t0;
    a1 = t1 > 0.f ? t1 : NEG * t1;
    a2 = t2 > 0.f ? t2 : NEG * t2;
}

// ---------------- softmax stats -> svw[e] = {src_bits, w0, w1, w2} ----------------
__global__ __launch_bounds__(256) void k_stats(const int* __restrict__ keyoff, const int* __restrict__ srcs,
                                               const float* __restrict__ qkd, float4* __restrict__ svw) {
    int node = blockIdx.x * 4 + (threadIdx.x >> 6);
    int lane = threadIdx.x & 63;
    int ko[9];
#pragma unroll
    for (int j = 0; j < 9; j++) ko[j] = keyoff[node * 8 + j];
    int beg = ko[0], end = ko[8], deg = end - beg;
    if (deg == 0) return;
    const float* qbase = qkd + (size_t)node * 48;

    if (deg <= 64) {
        float a0 = -INFINITY, a1 = -INFINITY, a2 = -INFINITY;
        int sv = 0;
        if (lane < deg) edge_alpha(beg + lane, ko, srcs, qkd, qbase, a0, a1, a2, sv);
        float m0 = a0, m1 = a1, m2 = a2;
#pragma unroll
        for (int off = 32; off >= 1; off >>= 1) {
            m0 = fmaxf(m0, __shfl_xor(m0, off));
            m1 = fmaxf(m1, __shfl_xor(m1, off));
            m2 = fmaxf(m2, __shfl_xor(m2, off));
        }
        float e0 = 0.f, e1 = 0.f, e2 = 0.f;
        if (lane < deg) {
            e0 = expf(a0 - m0);
            e1 = expf(a1 - m1);
            e2 = expf(a2 - m2);
        }
        float s0 = e0, s1 = e1, s2 = e2;
#pragma unroll
        for (int off = 32; off >= 1; off >>= 1) {
            s0 += __shfl_xor(s0, off);
            s1 += __shfl_xor(s1, off);
            s2 += __shfl_xor(s2, off);
        }
        float i0 = 1.f / (3.f * (s0 + 1e-16f));
        float i1 = 1.f / (3.f * (s1 + 1e-16f));
        float i2 = 1.f / (3.f * (s2 + 1e-16f));
        if (lane < deg)
            svw[beg + lane] = make_float4(__int_as_float(sv), e0 * i0, e1 * i1, e2 * i2);
    } else {
        float m0 = -INFINITY, m1 = -INFINITY, m2 = -INFINITY;
        for (int i = beg + lane; i < end; i += 64) {
            float a0, a1, a2; int sv;
            edge_alpha(i, ko, srcs, qkd, qbase, a0, a1, a2, sv);
            m0 = fmaxf(m0, a0); m1 = fmaxf(m1, a1); m2 = fmaxf(m2, a2);
        }
#pragma unroll
        for (int off = 32; off >= 1; off >>= 1) {
            m0 = fmaxf(m0, __shfl_xor(m0, off));
            m1 = fmaxf(m1, __shfl_xor(m1, off));
            m2 = fmaxf(m2, __shfl_xor(m2, off));
        }
        float s0 = 0.f, s1 = 0.f, s2 = 0.f;
        for (int i = beg + lane; i < end; i += 64) {
            float a0, a1, a2; int sv;
            edge_alpha(i, ko, srcs, qkd, qbase, a0, a1, a2, sv);
            s0 += expf(a0 - m0); s1 += expf(a1 - m1); s2 += expf(a2 - m2);
        }
#pragma unroll
        for (int off = 32; off >= 1; off >>= 1) {
            s0 += __shfl_xor(s0, off);
            s1 += __shfl_xor(s1, off);
            s2 += __shfl_xor(s2, off);
        }
        float i0 = 1.f / (3.f * (s0 + 1e-16f));
        float i1 = 1.f / (3.f * (s1 + 1e-16f));
        float i2 = 1.f / (3.f * (s2 + 1e-16f));
        for (int i = beg + lane; i < end; i += 64) {
            float a0, a1, a2; int sv;
            edge_alpha(i, ko, srcs, qkd, qbase, a0, a1, a2, sv);
            svw[i] = make_float4(__int_as_float(sv), expf(a0 - m0) * i0, expf(a1 - m1) * i1, expf(a2 - m2) * i2);
        }
    }
}

// ---------------- FUSED layer 1 (R12 structure) + atomic f32 accumulation ----------------
// grid (1250, 8). 16 nodes/block, quarter-wave per node, depth-2 pipelined gather.
#define PADK1 408
__global__ __launch_bounds__(256) void k_fused1(const int* __restrict__ keyoff, const float4* __restrict__ svw,
                                                const ushort_t* __restrict__ x, const ushort_t* __restrict__ wagg,
                                                float* __restrict__ x2pre) {
    __shared__ ushort_t lt[16][PADK1];  // 12.75 KB (only LDS)
    const int tid = threadIdx.x;
    const int w = tid >> 6, lane = tid & 63;
    const int q15 = lane & 15, kq = (lane >> 4) * 8;
    const int l15 = lane & 15;
    const int nbase = blockIdx.x * 16;
    const int r = blockIdx.y;
    const int mynode = w * 4 + (lane >> 4);
    const int key = (nbase + mynode) * 8 + r;

    const int beg = keyoff[key], end = keyoff[key + 1];
    const int deg = end - beg;
    float a0[8] = {}, a1[8] = {}, a2[8] = {};
    if (deg > 0) {
        float4 sw0 = svw[beg];
        float4 sw1;
        {
            int s = beg + 1;
            sw1 = svw[s < end ? s : beg];
            if (1 >= deg) { sw1.y = 0.f; sw1.z = 0.f; sw1.w = 0.f; }
        }
        ushort8_t xv0 = *(const ushort8_t*)&x[(size_t)__float_as_int(sw0.x) * 128 + q15 * 8];
        for (int i = 0; i < deg; i++) {
            float4 sw2;
            {
                int s = beg + i + 2;
                sw2 = svw[s < end ? s : beg];
                if (i + 2 >= deg) { sw2.y = 0.f; sw2.z = 0.f; sw2.w = 0.f; }
            }
            ushort8_t xv1 = *(const ushort8_t*)&x[(size_t)__float_as_int(sw1.x) * 128 + q15 * 8];
#pragma unroll
            for (int c = 0; c < 8; c++) {
                float f = b2f(xv0[c]);
                a0[c] += sw0.y * f;
                a1[c] += sw0.z * f;
                a2[c] += sw0.w * f;
            }
            sw0 = sw1;
            sw1 = sw2;
            xv0 = xv1;
        }
    }
    ushort8_t o0, o1, o2;
#pragma unroll
    for (int c = 0; c < 8; c++) {
        o0[c] = f2b(a0[c]);
        o1[c] = f2b(a1[c]);
        o2[c] = f2b(a2[c]);
    }
    *(ushort8_t*)&lt[mynode][0 * 128 + q15 * 8] = o0;
    *(ushort8_t*)&lt[mynode][1 * 128 + q15 * 8] = o1;
    *(ushort8_t*)&lt[mynode][2 * 128 + q15 * 8] = o2;
    __syncthreads();

    f32x4 acc = {};
#pragma unroll
    for (int ks = 0; ks < 12; ks++) {
        bf16x8 av = *(const bf16x8*)&lt[l15][ks * 32 + kq];
        bf16x8 bv = *(const bf16x8*)&wagg[(size_t)(w * 16 + l15) * 3072 + r * 384 + ks * 32 + kq];
        acc = __builtin_amdgcn_mfma_f32_16x16x32_bf16(av, bv, acc, 0, 0, 0);
    }
    const int r4 = (lane >> 4) * 4;
#pragma unroll
    for (int g = 0; g < 4; g++) {
        int row = nbase + r4 + g;
        atomicAdd(&x2pre[(size_t)row * 64 + w * 16 + l15], acc[g]);
    }
}

// ---------------- FUSED layer 2 (R12 structure) + atomic f32 accumulation ----------------
#define PADK2 208
__global__ __launch_bounds__(256) void k_fused2(const int* __restrict__ keyoff, const float4* __restrict__ svw,
                                                const ushort_t* __restrict__ x2in, const ushort_t* __restrict__ wagg,
                                                float* __restrict__ outpre) {
    __shared__ ushort_t lt[16][PADK2];  // 6.5 KB
    const int tid = threadIdx.x;
    const int w = tid >> 6, lane = tid & 63;
    const int q15 = lane & 15, kq = (lane >> 4) * 8;
    const int l15 = lane & 15;
    const int nbase = blockIdx.x * 16;
    const int r = blockIdx.y;
    const int mynode = w * 4 + (lane >> 4);
    const int key = (nbase + mynode) * 8 + r;

    const int beg = keyoff[key], end = keyoff[key + 1];
    const int deg = end - beg;
    float a0[4] = {}, a1[4] = {}, a2[4] = {};
    if (deg > 0) {
        float4 sw0 = svw[beg];
        float4 sw1;
        {
            int s = beg + 1;
            sw1 = svw[s < end ? s : beg];
            if (1 >= deg) { sw1.y = 0.f; sw1.z = 0.f; sw1.w = 0.f; }
        }
        ushort4_t xv0 = *(const ushort4_t*)&x2in[(size_t)__float_as_int(sw0.x) * 64 + q15 * 4];
        for (int i = 0; i < deg; i++) {
            float4 sw2;
            {
                int s = beg + i + 2;
                sw2 = svw[s < end ? s : beg];
                if (i + 2 >= deg) { sw2.y = 0.f; sw2.z = 0.f; sw2.w = 0.f; }
            }
            ushort4_t xv1 = *(const ushort4_t*)&x2in[(size_t)__float_as_int(sw1.x) * 64 + q15 * 4];
#pragma unroll
            for (int c = 0; c < 4; c++) {
                float f = b2f(xv0[c]);
                a0[c] += sw0.y * f;
                a1[c] += sw0.z * f;
                a2[c] += sw0.w * f;
            }
            sw0 = sw1;
            sw1 = sw2;
            xv0 = xv1;
        }
    }
    ushort4_t o0, o1, o2;
#pragma unroll
    for (int c = 0; c < 4; c++) {
        o0[c] = f2b(a0[c]);
        o1[c] = f2b(a1[c]);
        o2[c] = f2b(a2[c]);
    }
    *(ushort4_t*)&lt[mynode][0 * 64 + q15 * 4] = o0;
    *(ushort4_t*)&lt[mynode][1 * 64 + q15 * 4] = o1;
    *(ushort4_t*)&lt[mynode][2 * 64 + q15 * 4] = o2;
    __syncthreads();

    if (w == 0) {
        f32x4 acc = {};
#pragma unroll
        for (int ks = 0; ks < 6; ks++) {
            bf16x8 av = *(const bf16x8*)&lt[l15][ks * 32 + kq];
            bf16x8 bv = *(const bf16x8*)&wagg[(size_t)l15 * 1536 + r * 192 + ks * 32 + kq];
            acc = __builtin_amdgcn_mfma_f32_16x16x32_bf16(av, bv, acc, 0, 0, 0);
        }
        const int r4 = (lane >> 4) * 4;
#pragma unroll
        for (int g = 0; g < 4; g++)
            atomicAdd(&outpre[(size_t)(nbase + r4 + g) * 16 + l15], acc[g]);
    }
}

// ---------------- bias + relu -> bf16 x2 ----------------
__global__ __launch_bounds__(256) void k_reduce1(const float* __restrict__ x2pre, const float* __restrict__ bias,
                                                 ushort_t* __restrict__ x2) {
    int idx = blockIdx.x * blockDim.x + threadIdx.x;
    const int MN = N_NODES * 64;
    if (idx >= MN) return;
    float s = x2pre[idx] + bias[idx & 63];
    x2[idx] = f2b(s > 0.f ? s : 0.f);
}

// ---------------- bias + sigmoid -> out f32 ----------------
__global__ __launch_bounds__(256) void k_reduce2(const float* __restrict__ outpre, const float* __restrict__ bias,
                                                 float* __restrict__ outp) {
    int idx = blockIdx.x * blockDim.x + threadIdx.x;
    const int MN = N_NODES * 16;
    if (idx >= MN) return;
    float s = outpre[idx] + bias[idx & 15];
    outp[idx] = 1.f / (1.f + expf(-s));
}

extern "C" void kernel_launch(void* const* d_in, const int* in_sizes, int n_in, void* d_out, int out_size,
                              void* d_ws, size_t ws_size, hipStream_t stream) {
    const float* emb = (const float*)d_in[0];
    const float* w1 = (const float*)d_in[1];
    const float* q1 = (const float*)d_in[2];
    const float* k1 = (const float*)d_in[3];
    const float* b1 = (const float*)d_in[4];
    const float* w2 = (const float*)d_in[5];
    const float* q2 = (const float*)d_in[6];
    const float* k2 = (const float*)d_in[7];
    const float* b2 = (const float*)d_in[8];
    const int* eidx = (const int*)d_in[9];
    const int* etype = (const int*)d_in[10];
    const int* srcv = eidx;
    const int* dstv = eidx + N_EDGES;
    float* out = (float*)d_out;

    char* p = (char*)d_ws;
    auto alloc = [&](size_t bytes) -> void* {
        void* q = p;
        p += (bytes + 255) & ~(size_t)255;
        return q;
    };
    int* counts = (int*)alloc((size_t)NKEYS * 4);
    int* keyoff = (int*)alloc((size_t)(NKEYS + 1) * 4);
    int* cursor = (int*)alloc((size_t)NKEYS * 4);
    int* blocksum = (int*)alloc((size_t)SCAN_NBLK * 4);
    int* blockbase = (int*)alloc((size_t)SCAN_NBLK * 4);
    int* srcs = (int*)alloc((size_t)N_EDGES * 4);
    float4* svw = (float4*)alloc((size_t)N_EDGES * 16);
    ushort_t* emb_b = (ushort_t*)alloc((size_t)N_NODES * EMB * 2);
    ushort_t* wqkt1 = (ushort_t*)alloc((size_t)48 * 128 * 2);
    ushort_t* wagg1 = (ushort_t*)alloc((size_t)64 * 3072 * 2);
    ushort_t* wqkt2 = (ushort_t*)alloc((size_t)48 * 64 * 2);
    ushort_t* wagg2 = (ushort_t*)alloc((size_t)16 * 1536 * 2);
    float* qkd = (float*)alloc((size_t)N_NODES * 48 * 4);
    ushort_t* x2 = (ushort_t*)alloc((size_t)N_NODES * 64 * 2);
    float* x2pre = (float*)alloc((size_t)N_NODES * 64 * 4);
    float* outpre = (float*)alloc((size_t)N_NODES * 16 * 4);

    // ---- merged precomputes + accumulator zeroing ----
    k_prep<<<(PREP_TOT + 255) / 256, 256, 0, stream>>>(emb, emb_b, w1, q1, k1, wqkt1, w2, q2, k2, wqkt2, wagg1,
                                                       wagg2);
    hipMemsetAsync(x2pre, 0, (size_t)N_NODES * 64 * 4, stream);
    hipMemsetAsync(outpre, 0, (size_t)N_NODES * 16 * 4, stream);

    // ---- CSR over (dst, rel) ----
    hipMemsetAsync(counts, 0, (size_t)NKEYS * 4, stream);
    k_count<<<(N_EDGES + 255) / 256, 256, 0, stream>>>(dstv, etype, counts);
    k_scanA<<<SCAN_NBLK, 256, 0, stream>>>(counts, keyoff, blocksum);
    k_scanB<<<1, 256, 0, stream>>>(blocksum, blockbase, keyoff);
    k_scanC<<<SCAN_NBLK, 256, 0, stream>>>(blockbase, keyoff, cursor);
    k_scatter<<<(N_EDGES + 255) / 256, 256, 0, stream>>>(srcv, dstv, etype, cursor, srcs);

    // ---- layer 1 ----
    k_mfma_gemm<128, 128, 48, 1, 3><<<dim3(313, 1), 256, 0, stream>>>(emb_b, wqkt1, qkd, N_NODES);
    k_stats<<<N_NODES / 4, 256, 0, stream>>>(keyoff, srcs, qkd, svw);
    k_fused1<<<dim3(N_NODES / 16, 8), 256, 0, stream>>>(keyoff, svw, emb_b, wagg1, x2pre);
    k_reduce1<<<(N_NODES * 64 + 255) / 256, 256, 0, stream>>>(x2pre, b1, x2);

    // ---- layer 2 ----
    k_mfma_gemm<64, 64, 48, 1, 3><<<dim3(313, 1), 256, 0, stream>>>(x2, wqkt2, qkd, N_NODES);
    k_stats<<<N_NODES / 4, 256, 0, stream>>>(keyoff, srcs, qkd, svw);
    k_fused2<<<dim3(N_NODES / 16, 8), 256, 0, stream>>>(keyoff, svw, x2, wagg2, outpre);
    k_reduce2<<<(N_NODES * 16 + 255) / 256, 256, 0, stream>>>(outpre, b2, out);
}

// Round 17
// 230.329 us; speedup vs baseline: 1.3010x; 1.0629x over previous
//
#include <hip/hip_runtime.h>
#include <hip/hip_bf16.h>
#include <math.h>

#define N_NODES 20000
#define EMB 128
#define HID 64
#define RELS 8
#define CLS 16
#define N_EDGES 640000
#define NEG 0.2f
#define NKEYS (N_NODES * RELS)
#define SCAN_CHUNK 1024
#define SCAN_NBLK ((NKEYS + SCAN_CHUNK - 1) / SCAN_CHUNK)  // 157

typedef unsigned short ushort_t;
typedef __attribute__((ext_vector_type(8))) short bf16x8;
typedef __attribute__((ext_vector_type(8))) unsigned short ushort8_t;
typedef __attribute__((ext_vector_type(4))) unsigned short ushort4_t;
typedef __attribute__((ext_vector_type(4))) float f32x4;

__device__ __forceinline__ float b2f(ushort_t u) {
    return __uint_as_float(((unsigned int)u) << 16);
}
__device__ __forceinline__ ushort_t f2b(float f) {
    __hip_bfloat16 h = __float2bfloat16(f);
    return *reinterpret_cast<ushort_t*>(&h);
}

// ---------------- merged precompute: cvt + wqk + wagg + count + zeroing ----------------
__device__ __forceinline__ void prep_cvt(int i, const float* __restrict__ in, ushort_t* __restrict__ outp) {
    float4 v = *(const float4*)&in[(size_t)i * 4];
    ushort4 o;
    o.x = f2b(v.x); o.y = f2b(v.y); o.z = f2b(v.z); o.w = f2b(v.w);
    *(ushort4*)&outp[(size_t)i * 4] = o;
}

template <int D, int OUT>
__device__ __forceinline__ void prep_wqk(int tid, const float* __restrict__ w, const float* __restrict__ q,
                                         const float* __restrict__ k, ushort_t* __restrict__ wqkt) {
    int c = tid / D, i = tid % D;
    int r = c / 6, j = c % 6;
    const float* qk = (j < 3) ? q : k;
    int jj = (j < 3) ? j : j - 3;
    const float* wrow = w + ((size_t)r * D + i) * OUT;
    float s = 0.f;
    for (int o = 0; o < OUT; o++) s += wrow[o] * qk[o * 3 + jj];
    wqkt[(size_t)c * D + i] = f2b(s);
}

template <int D, int OC>
__device__ __forceinline__ void prep_wagg(int tid, const float* __restrict__ w, ushort_t* __restrict__ outp) {
    const int KT = RELS * 3 * D;
    int kidx = tid % KT;
    int o = tid / KT;
    int r = kidx / (3 * D), h = (kidx / D) % 3, i = kidx % D;
    outp[tid] = f2b(w[((size_t)r * D + i) * (3 * OC) + h * OC + o]);
}

#define PREP_N0 (N_NODES * EMB / 4)
#define PREP_N1 (48 * 128)
#define PREP_N2 (48 * 64)
#define PREP_N3 (64 * 3072)
#define PREP_N4 (16 * 1536)
#define PREP_N5 N_EDGES          // count
#define PREP_N6 (N_NODES * 16)   // zero x2pre (float4)
#define PREP_N7 (N_NODES * 4)    // zero outpre (float4)
#define PREP_TOT (PREP_N0 + PREP_N1 + PREP_N2 + PREP_N3 + PREP_N4 + PREP_N5 + PREP_N6 + PREP_N7)

__global__ __launch_bounds__(256) void k_prep(const float* __restrict__ emb, ushort_t* __restrict__ emb_b,
                                              const float* __restrict__ w1, const float* __restrict__ q1,
                                              const float* __restrict__ k1, ushort_t* __restrict__ wqkt1,
                                              const float* __restrict__ w2, const float* __restrict__ q2,
                                              const float* __restrict__ k2, ushort_t* __restrict__ wqkt2,
                                              ushort_t* __restrict__ wagg1, ushort_t* __restrict__ wagg2,
                                              const int* __restrict__ dstv, const int* __restrict__ etype,
                                              int* __restrict__ counts, float* __restrict__ x2pre,
                                              float* __restrict__ outpre) {
    int tid = blockIdx.x * 256 + threadIdx.x;
    if (tid < PREP_N0) { prep_cvt(tid, emb, emb_b); return; }
    tid -= PREP_N0;
    if (tid < PREP_N1) { prep_wqk<128, 192>(tid, w1, q1, k1, wqkt1); return; }
    tid -= PREP_N1;
    if (tid < PREP_N2) { prep_wqk<64, 48>(tid, w2, q2, k2, wqkt2); return; }
    tid -= PREP_N2;
    if (tid < PREP_N3) { prep_wagg<128, 64>(tid, w1, wagg1); return; }
    tid -= PREP_N3;
    if (tid < PREP_N4) { prep_wagg<64, 16>(tid, w2, wagg2); return; }
    tid -= PREP_N4;
    if (tid < PREP_N5) { atomicAdd(&counts[dstv[tid] * 8 + etype[tid]], 1); return; }
    tid -= PREP_N5;
    if (tid < PREP_N6) { *(float4*)&x2pre[(size_t)tid * 4] = make_float4(0.f, 0.f, 0.f, 0.f); return; }
    tid -= PREP_N6;
    if (tid < PREP_N7) { *(float4*)&outpre[(size_t)tid * 4] = make_float4(0.f, 0.f, 0.f, 0.f); return; }
}

// ---------------- hierarchical scan ----------------
__global__ __launch_bounds__(256) void k_scanA(const int* __restrict__ counts, int* __restrict__ keyoff,
                                               int* __restrict__ blocksum) {
    __shared__ int part[256];
    int b = blockIdx.x, tid = threadIdx.x;
    int base = b * SCAN_CHUNK + tid * 4;
    int4 c = make_int4(0, 0, 0, 0);
    if (base + 3 < NKEYS) c = *(const int4*)&counts[base];
    else {
        if (base + 0 < NKEYS) c.x = counts[base + 0];
        if (base + 1 < NKEYS) c.y = counts[base + 1];
        if (base + 2 < NKEYS) c.z = counts[base + 2];
        if (base + 3 < NKEYS) c.w = counts[base + 3];
    }
    int s = c.x + c.y + c.z + c.w;
    part[tid] = s;
    __syncthreads();
    for (int off = 1; off < 256; off <<= 1) {
        int v = (tid >= off) ? part[tid - off] : 0;
        __syncthreads();
        part[tid] += v;
        __syncthreads();
    }
    int excl = part[tid] - s;
    int4 o;
    o.x = excl;
    o.y = excl + c.x;
    o.z = excl + c.x + c.y;
    o.w = excl + c.x + c.y + c.z;
    if (base + 3 < NKEYS) *(int4*)&keyoff[base] = o;
    else {
        if (base + 0 < NKEYS) keyoff[base + 0] = o.x;
        if (base + 1 < NKEYS) keyoff[base + 1] = o.y;
        if (base + 2 < NKEYS) keyoff[base + 2] = o.z;
        if (base + 3 < NKEYS) keyoff[base + 3] = o.w;
    }
    if (tid == 255) blocksum[b] = part[255];
}

__global__ __launch_bounds__(256) void k_scanB(int* __restrict__ blocksum, int* __restrict__ blockbase,
                                               int* __restrict__ keyoff) {
    __shared__ int part[256];
    int tid = threadIdx.x;
    int v0 = (tid < SCAN_NBLK) ? blocksum[tid] : 0;
    part[tid] = v0;
    __syncthreads();
    for (int off = 1; off < 256; off <<= 1) {
        int v = (tid >= off) ? part[tid - off] : 0;
        __syncthreads();
        part[tid] += v;
        __syncthreads();
    }
    if (tid < SCAN_NBLK) blockbase[tid] = part[tid] - v0;
    if (tid == 255) keyoff[NKEYS] = part[255];
}

__global__ __launch_bounds__(256) void k_scanC(const int* __restrict__ blockbase, int* __restrict__ keyoff,
                                               int* __restrict__ cursor) {
    int b = blockIdx.x, tid = threadIdx.x;
    int base = b * SCAN_CHUNK + tid * 4;
    int add = blockbase[b];
    if (base + 3 < NKEYS) {
        int4 v = *(const int4*)&keyoff[base];
        v.x += add; v.y += add; v.z += add; v.w += add;
        *(int4*)&keyoff[base] = v;
        *(int4*)&cursor[base] = v;
    } else {
        for (int j = 0; j < 4; j++) {
            if (base + j < NKEYS) {
                int v = keyoff[base + j] + add;
                keyoff[base + j] = v;
                cursor[base + j] = v;
            }
        }
    }
}

// ---------------- scatter srcs into CSR order ----------------
__global__ __launch_bounds__(256) void k_scatter(const int* __restrict__ src, const int* __restrict__ dst,
                                                 const int* __restrict__ et, int* __restrict__ cursor,
                                                 int* __restrict__ srcs) {
    int e = blockIdx.x * blockDim.x + threadIdx.x;
    if (e < N_EDGES) {
        int p = atomicAdd(&cursor[dst[e] * 8 + et[e]], 1);
        srcs[p] = src[e];
    }
}

// ---------------- direct-fragment MFMA GEMM (layer-1 qkd projection) ----------------
template <int K, int KCH, int N, int MREP, int NREP>
__global__ __launch_bounds__(256) void k_mfma_gemm(const ushort_t* __restrict__ A, const ushort_t* __restrict__ Bt,
                                                   float* __restrict__ outp, int M) {
    const int wid = threadIdx.x >> 6;
    const int lane = threadIdx.x & 63;
    const int m0 = blockIdx.x * (4 * MREP * 16) + wid * (MREP * 16);
    const int kbase = blockIdx.y * KCH;
    const int l15 = lane & 15;
    const int kq = (lane >> 4) * 8;

    f32x4 acc[MREP][NREP] = {};
    for (int kk = kbase; kk < kbase + KCH; kk += 32) {
        bf16x8 a[MREP], b[NREP];
#pragma unroll
        for (int i = 0; i < MREP; i++) {
            int row = m0 + i * 16 + l15;
            row = row < M ? row : M - 1;
            a[i] = *(const bf16x8*)&A[(size_t)row * K + kk + kq];
        }
#pragma unroll
        for (int j = 0; j < NREP; j++) b[j] = *(const bf16x8*)&Bt[(size_t)(j * 16 + l15) * K + kk + kq];
#pragma unroll
        for (int i = 0; i < MREP; i++)
#pragma unroll
            for (int j = 0; j < NREP; j++)
                acc[i][j] = __builtin_amdgcn_mfma_f32_16x16x32_bf16(a[i], b[j], acc[i][j], 0, 0, 0);
    }
    float* op = outp + (size_t)blockIdx.y * M * N;
    const int r4 = (lane >> 4) * 4;
#pragma unroll
    for (int i = 0; i < MREP; i++) {
#pragma unroll
        for (int j = 0; j < NREP; j++) {
#pragma unroll
            for (int g = 0; g < 4; g++) {
                int row = m0 + i * 16 + r4 + g;
                if (row < M) op[(size_t)row * N + j * 16 + l15] = acc[i][j][g];
            }
        }
    }
}

// ---------------- layer-2 qkd GEMM with fused bias+relu epilogue-prologue ----------------
// reads x2pre f32, applies bias+relu, writes x2 bf16, computes qkd = relu(x2) @ wqkt2^T
__global__ __launch_bounds__(256) void k_gemm2f(const float* __restrict__ x2pre, const float* __restrict__ bias,
                                                const ushort_t* __restrict__ Bt, ushort_t* __restrict__ x2,
                                                float* __restrict__ qkd) {
    const int wid = threadIdx.x >> 6;
    const int lane = threadIdx.x & 63;
    const int m0 = blockIdx.x * 64 + wid * 16;
    const int l15 = lane & 15;
    const int kq = (lane >> 4) * 8;

    f32x4 acc[3] = {};
#pragma unroll
    for (int kk = 0; kk < 64; kk += 32) {
        int row = m0 + l15;
        row = row < N_NODES ? row : N_NODES - 1;
        int col = kk + kq;
        float4 f0 = *(const float4*)&x2pre[(size_t)row * 64 + col];
        float4 f1 = *(const float4*)&x2pre[(size_t)row * 64 + col + 4];
        float fv[8] = {f0.x, f0.y, f0.z, f0.w, f1.x, f1.y, f1.z, f1.w};
        bf16x8 av;
#pragma unroll
        for (int c = 0; c < 8; c++) {
            float s = fv[c] + bias[col + c];
            s = s > 0.f ? s : 0.f;
            av[c] = (short)f2b(s);
        }
        *(bf16x8*)&x2[(size_t)row * 64 + col] = av;
#pragma unroll
        for (int j = 0; j < 3; j++) {
            bf16x8 bv = *(const bf16x8*)&Bt[(size_t)(j * 16 + l15) * 64 + col];
            acc[j] = __builtin_amdgcn_mfma_f32_16x16x32_bf16(av, bv, acc[j], 0, 0, 0);
        }
    }
    const int r4 = (lane >> 4) * 4;
#pragma unroll
    for (int j = 0; j < 3; j++) {
#pragma unroll
        for (int g = 0; g < 4; g++) {
            int row = m0 + r4 + g;
            if (row < N_NODES) qkd[(size_t)row * 48 + j * 16 + l15] = acc[j][g];
        }
    }
}

// ---------------- per-edge alpha from qkd (on the fly), also returns src ----------------
__device__ __forceinline__ void edge_alpha(int s_idx, const int (&ko)[9], const int* __restrict__ srcs,
                                           const float* __restrict__ qkd, const float* __restrict__ qbase,
                                           float& a0, float& a1, float& a2, int& sv) {
    int r = 0;
#pragma unroll
    for (int j = 1; j < 8; j++) r += (s_idx >= ko[j]) ? 1 : 0;
    sv = srcs[s_idx];
    const float* kd = qkd + (size_t)sv * 48 + r * 6 + 3;
    const float* qd = qbase + r * 6;
    float t0 = qd[0] + kd[0], t1 = qd[1] + kd[1], t2 = qd[2] + kd[2];
    a0 = t0 > 0.f ? t0 : NEG * t0;
    a1 = t1 > 0.f ? t1 : NEG * t1;
    a2 = t2 > 0.f ? t2 : NEG * t2;
}

__device__ __forceinline__ ushort4_t pack_svw(int sv, float w0, float w1, float w2) {
    ushort4_t v;
    v[0] = (ushort_t)sv;
    v[1] = f2b(w0);
    v[2] = f2b(w1);
    v[3] = f2b(w2);
    return v;
}

// ---------------- softmax stats -> packed svw8[e] = {u16 src, bf16 w0,w1,w2} ----------------
__global__ __launch_bounds__(256) void k_stats(const int* __restrict__ keyoff, const int* __restrict__ srcs,
                                               const float* __restrict__ qkd, ushort4_t* __restrict__ svw8) {
    int node = blockIdx.x * 4 + (threadIdx.x >> 6);
    int lane = threadIdx.x & 63;
    int ko[9];
#pragma unroll
    for (int j = 0; j < 9; j++) ko[j] = keyoff[node * 8 + j];
    int beg = ko[0], end = ko[8], deg = end - beg;
    if (deg == 0) return;
    const float* qbase = qkd + (size_t)node * 48;

    if (deg <= 64) {
        float a0 = -INFINITY, a1 = -INFINITY, a2 = -INFINITY;
        int sv = 0;
        if (lane < deg) edge_alpha(beg + lane, ko, srcs, qkd, qbase, a0, a1, a2, sv);
        float m0 = a0, m1 = a1, m2 = a2;
#pragma unroll
        for (int off = 32; off >= 1; off >>= 1) {
            m0 = fmaxf(m0, __shfl_xor(m0, off));
            m1 = fmaxf(m1, __shfl_xor(m1, off));
            m2 = fmaxf(m2, __shfl_xor(m2, off));
        }
        float e0 = 0.f, e1 = 0.f, e2 = 0.f;
        if (lane < deg) {
            e0 = expf(a0 - m0);
            e1 = expf(a1 - m1);
            e2 = expf(a2 - m2);
        }
        float s0 = e0, s1 = e1, s2 = e2;
#pragma unroll
        for (int off = 32; off >= 1; off >>= 1) {
            s0 += __shfl_xor(s0, off);
            s1 += __shfl_xor(s1, off);
            s2 += __shfl_xor(s2, off);
        }
        float i0 = 1.f / (3.f * (s0 + 1e-16f));
        float i1 = 1.f / (3.f * (s1 + 1e-16f));
        float i2 = 1.f / (3.f * (s2 + 1e-16f));
        if (lane < deg) svw8[beg + lane] = pack_svw(sv, e0 * i0, e1 * i1, e2 * i2);
    } else {
        float m0 = -INFINITY, m1 = -INFINITY, m2 = -INFINITY;
        for (int i = beg + lane; i < end; i += 64) {
            float a0, a1, a2; int sv;
            edge_alpha(i, ko, srcs, qkd, qbase, a0, a1, a2, sv);
            m0 = fmaxf(m0, a0); m1 = fmaxf(m1, a1); m2 = fmaxf(m2, a2);
        }
#pragma unroll
        for (int off = 32; off >= 1; off >>= 1) {
            m0 = fmaxf(m0, __shfl_xor(m0, off));
            m1 = fmaxf(m1, __shfl_xor(m1, off));
            m2 = fmaxf(m2, __shfl_xor(m2, off));
        }
        float s0 = 0.f, s1 = 0.f, s2 = 0.f;
        for (int i = beg + lane; i < end; i += 64) {
            float a0, a1, a2; int sv;
            edge_alpha(i, ko, srcs, qkd, qbase, a0, a1, a2, sv);
            s0 += expf(a0 - m0); s1 += expf(a1 - m1); s2 += expf(a2 - m2);
        }
#pragma unroll
        for (int off = 32; off >= 1; off >>= 1) {
            s0 += __shfl_xor(s0, off);
            s1 += __shfl_xor(s1, off);
            s2 += __shfl_xor(s2, off);
        }
        float i0 = 1.f / (3.f * (s0 + 1e-16f));
        float i1 = 1.f / (3.f * (s1 + 1e-16f));
        float i2 = 1.f / (3.f * (s2 + 1e-16f));
        for (int i = beg + lane; i < end; i += 64) {
            float a0, a1, a2; int sv;
            edge_alpha(i, ko, srcs, qkd, qbase, a0, a1, a2, sv);
            svw8[i] = pack_svw(sv, expf(a0 - m0) * i0, expf(a1 - m1) * i1, expf(a2 - m2) * i2);
        }
    }
}

// ---------------- FUSED layer 1: depth-2 pipelined gather + MFMA + atomic f32 ----------------
#define PADK1 408
__global__ __launch_bounds__(256) void k_fused1(const int* __restrict__ keyoff, const ushort4_t* __restrict__ svw8,
                                                const ushort_t* __restrict__ x, const ushort_t* __restrict__ wagg,
                                                float* __restrict__ x2pre) {
    __shared__ ushort_t lt[16][PADK1];  // 12.75 KB
    const int tid = threadIdx.x;
    const int w = tid >> 6, lane = tid & 63;
    const int q15 = lane & 15, kq = (lane >> 4) * 8;
    const int l15 = lane & 15;
    const int nbase = blockIdx.x * 16;
    const int r = blockIdx.y;
    const int mynode = w * 4 + (lane >> 4);
    const int key = (nbase + mynode) * 8 + r;

    const int beg = keyoff[key], end = keyoff[key + 1];
    const int deg = end - beg;
    float a0[8] = {}, a1[8] = {}, a2[8] = {};
    if (deg > 0) {
        ushort4_t sw0 = svw8[beg];
        ushort4_t sw1;
        {
            int s = beg + 1;
            sw1 = svw8[s < end ? s : beg];
            if (1 >= deg) { sw1[1] = 0; sw1[2] = 0; sw1[3] = 0; }
        }
        ushort8_t xv0 = *(const ushort8_t*)&x[(size_t)sw0[0] * 128 + q15 * 8];
        for (int i = 0; i < deg; i++) {
            ushort4_t sw2;
            {
                int s = beg + i + 2;
                sw2 = svw8[s < end ? s : beg];
                if (i + 2 >= deg) { sw2[1] = 0; sw2[2] = 0; sw2[3] = 0; }
            }
            ushort8_t xv1 = *(const ushort8_t*)&x[(size_t)sw1[0] * 128 + q15 * 8];
            float w0 = b2f(sw0[1]), w1 = b2f(sw0[2]), w2 = b2f(sw0[3]);
#pragma unroll
            for (int c = 0; c < 8; c++) {
                float f = b2f(xv0[c]);
                a0[c] += w0 * f;
                a1[c] += w1 * f;
                a2[c] += w2 * f;
            }
            sw0 = sw1;
            sw1 = sw2;
            xv0 = xv1;
        }
    }
    ushort8_t o0, o1, o2;
#pragma unroll
    for (int c = 0; c < 8; c++) {
        o0[c] = f2b(a0[c]);
        o1[c] = f2b(a1[c]);
        o2[c] = f2b(a2[c]);
    }
    *(ushort8_t*)&lt[mynode][0 * 128 + q15 * 8] = o0;
    *(ushort8_t*)&lt[mynode][1 * 128 + q15 * 8] = o1;
    *(ushort8_t*)&lt[mynode][2 * 128 + q15 * 8] = o2;
    __syncthreads();

    f32x4 acc = {};
#pragma unroll
    for (int ks = 0; ks < 12; ks++) {
        bf16x8 av = *(const bf16x8*)&lt[l15][ks * 32 + kq];
        bf16x8 bv = *(const bf16x8*)&wagg[(size_t)(w * 16 + l15) * 3072 + r * 384 + ks * 32 + kq];
        acc = __builtin_amdgcn_mfma_f32_16x16x32_bf16(av, bv, acc, 0, 0, 0);
    }
    const int r4 = (lane >> 4) * 4;
#pragma unroll
    for (int g = 0; g < 4; g++) {
        int row = nbase + r4 + g;
        atomicAdd(&x2pre[(size_t)row * 64 + w * 16 + l15], acc[g]);
    }
}

// ---------------- FUSED layer 2: depth-2 pipelined gather + MFMA + atomic f32 ----------------
#define PADK2 208
__global__ __launch_bounds__(256) void k_fused2(const int* __restrict__ keyoff, const ushort4_t* __restrict__ svw8,
                                                const ushort_t* __restrict__ x2in, const ushort_t* __restrict__ wagg,
                                                float* __restrict__ outpre) {
    __shared__ ushort_t lt[16][PADK2];  // 6.5 KB
    const int tid = threadIdx.x;
    const int w = tid >> 6, lane = tid & 63;
    const int q15 = lane & 15, kq = (lane >> 4) * 8;
    const int l15 = lane & 15;
    const int nbase = blockIdx.x * 16;
    const int r = blockIdx.y;
    const int mynode = w * 4 + (lane >> 4);
    const int key = (nbase + mynode) * 8 + r;

    const int beg = keyoff[key], end = keyoff[key + 1];
    const int deg = end - beg;
    float a0[4] = {}, a1[4] = {}, a2[4] = {};
    if (deg > 0) {
        ushort4_t sw0 = svw8[beg];
        ushort4_t sw1;
        {
            int s = beg + 1;
            sw1 = svw8[s < end ? s : beg];
            if (1 >= deg) { sw1[1] = 0; sw1[2] = 0; sw1[3] = 0; }
        }
        ushort4_t xv0 = *(const ushort4_t*)&x2in[(size_t)sw0[0] * 64 + q15 * 4];
        for (int i = 0; i < deg; i++) {
            ushort4_t sw2;
            {
                int s = beg + i + 2;
                sw2 = svw8[s < end ? s : beg];
                if (i + 2 >= deg) { sw2[1] = 0; sw2[2] = 0; sw2[3] = 0; }
            }
            ushort4_t xv1 = *(const ushort4_t*)&x2in[(size_t)sw1[0] * 64 + q15 * 4];
            float w0 = b2f(sw0[1]), w1 = b2f(sw0[2]), w2 = b2f(sw0[3]);
#pragma unroll
            for (int c = 0; c < 4; c++) {
                float f = b2f(xv0[c]);
                a0[c] += w0 * f;
                a1[c] += w1 * f;
                a2[c] += w2 * f;
            }
            sw0 = sw1;
            sw1 = sw2;
            xv0 = xv1;
        }
    }
    ushort4_t o0, o1, o2;
#pragma unroll
    for (int c = 0; c < 4; c++) {
        o0[c] = f2b(a0[c]);
        o1[c] = f2b(a1[c]);
        o2[c] = f2b(a2[c]);
    }
    *(ushort4_t*)&lt[mynode][0 * 64 + q15 * 4] = o0;
    *(ushort4_t*)&lt[mynode][1 * 64 + q15 * 4] = o1;
    *(ushort4_t*)&lt[mynode][2 * 64 + q15 * 4] = o2;
    __syncthreads();

    if (w == 0) {
        f32x4 acc = {};
#pragma unroll
        for (int ks = 0; ks < 6; ks++) {
            bf16x8 av = *(const bf16x8*)&lt[l15][ks * 32 + kq];
            bf16x8 bv = *(const bf16x8*)&wagg[(size_t)l15 * 1536 + r * 192 + ks * 32 + kq];
            acc = __builtin_amdgcn_mfma_f32_16x16x32_bf16(av, bv, acc, 0, 0, 0);
        }
        const int r4 = (lane >> 4) * 4;
#pragma unroll
        for (int g = 0; g < 4; g++)
            atomicAdd(&outpre[(size_t)(nbase + r4 + g) * 16 + l15], acc[g]);
    }
}

// ---------------- bias + sigmoid -> out f32 ----------------
__global__ __launch_bounds__(256) void k_reduce2(const float* __restrict__ outpre, const float* __restrict__ bias,
                                                 float* __restrict__ outp) {
    int idx = blockIdx.x * blockDim.x + threadIdx.x;
    const int MN = N_NODES * 16;
    if (idx >= MN) return;
    float s = outpre[idx] + bias[idx & 15];
    outp[idx] = 1.f / (1.f + expf(-s));
}

extern "C" void kernel_launch(void* const* d_in, const int* in_sizes, int n_in, void* d_out, int out_size,
                              void* d_ws, size_t ws_size, hipStream_t stream) {
    const float* emb = (const float*)d_in[0];
    const float* w1 = (const float*)d_in[1];
    const float* q1 = (const float*)d_in[2];
    const float* k1 = (const float*)d_in[3];
    const float* b1 = (const float*)d_in[4];
    const float* w2 = (const float*)d_in[5];
    const float* q2 = (const float*)d_in[6];
    const float* k2 = (const float*)d_in[7];
    const float* b2 = (const float*)d_in[8];
    const int* eidx = (const int*)d_in[9];
    const int* etype = (const int*)d_in[10];
    const int* srcv = eidx;
    const int* dstv = eidx + N_EDGES;
    float* out = (float*)d_out;

    char* p = (char*)d_ws;
    auto alloc = [&](size_t bytes) -> void* {
        void* q = p;
        p += (bytes + 255) & ~(size_t)255;
        return q;
    };
    int* counts = (int*)alloc((size_t)NKEYS * 4);
    int* keyoff = (int*)alloc((size_t)(NKEYS + 1) * 4);
    int* cursor = (int*)alloc((size_t)NKEYS * 4);
    int* blocksum = (int*)alloc((size_t)SCAN_NBLK * 4);
    int* blockbase = (int*)alloc((size_t)SCAN_NBLK * 4);
    int* srcs = (int*)alloc((size_t)N_EDGES * 4);
    ushort4_t* svw8 = (ushort4_t*)alloc((size_t)N_EDGES * 8);
    ushort_t* emb_b = (ushort_t*)alloc((size_t)N_NODES * EMB * 2);
    ushort_t* wqkt1 = (ushort_t*)alloc((size_t)48 * 128 * 2);
    ushort_t* wagg1 = (ushort_t*)alloc((size_t)64 * 3072 * 2);
    ushort_t* wqkt2 = (ushort_t*)alloc((size_t)48 * 64 * 2);
    ushort_t* wagg2 = (ushort_t*)alloc((size_t)16 * 1536 * 2);
    float* qkd = (float*)alloc((size_t)N_NODES * 48 * 4);
    ushort_t* x2 = (ushort_t*)alloc((size_t)N_NODES * 64 * 2);
    float* x2pre = (float*)alloc((size_t)N_NODES * 64 * 4);
    float* outpre = (float*)alloc((size_t)N_NODES * 16 * 4);

    // counts must be zero before k_prep's count range runs (stream-ordered)
    hipMemsetAsync(counts, 0, (size_t)NKEYS * 4, stream);
    k_prep<<<(PREP_TOT + 255) / 256, 256, 0, stream>>>(emb, emb_b, w1, q1, k1, wqkt1, w2, q2, k2, wqkt2, wagg1,
                                                       wagg2, dstv, etype, counts, x2pre, outpre);

    // ---- CSR over (dst, rel) ----
    k_scanA<<<SCAN_NBLK, 256, 0, stream>>>(counts, keyoff, blocksum);
    k_scanB<<<1, 256, 0, stream>>>(blocksum, blockbase, keyoff);
    k_scanC<<<SCAN_NBLK, 256, 0, stream>>>(blockbase, keyoff, cursor);
    k_scatter<<<(N_EDGES + 255) / 256, 256, 0, stream>>>(srcv, dstv, etype, cursor, srcs);

    // ---- layer 1 ----
    k_mfma_gemm<128, 128, 48, 1, 3><<<dim3(313, 1), 256, 0, stream>>>(emb_b, wqkt1, qkd, N_NODES);
    k_stats<<<N_NODES / 4, 256, 0, stream>>>(keyoff, srcs, qkd, svw8);
    k_fused1<<<dim3(N_NODES / 16, 8), 256, 0, stream>>>(keyoff, svw8, emb_b, wagg1, x2pre);

    // ---- layer 2 (bias+relu fused into qkd GEMM) ----
    k_gemm2f<<<dim3(313), 256, 0, stream>>>(x2pre, b1, wqkt2, x2, qkd);
    k_stats<<<N_NODES / 4, 256, 0, stream>>>(keyoff, srcs, qkd, svw8);
    k_fused2<<<dim3(N_NODES / 16, 8), 256, 0, stream>>>(keyoff, svw8, x2, wagg2, outpre);
    k_reduce2<<<(N_NODES * 16 + 255) / 256, 256, 0, stream>>>(outpre, b2, out);
}

// Round 18
// 211.097 us; speedup vs baseline: 1.4196x; 1.0911x over previous
//
#include <hip/hip_runtime.h>
#include <hip/hip_bf16.h>
#include <math.h>

#define N_NODES 20000
#define EMB 128
#define HID 64
#define RELS 8
#define CLS 16
#define N_EDGES 640000
#define NEG 0.2f
#define NKEYS (N_NODES * RELS)
#define SCAN_CHUNK 1024
#define SCAN_NBLK ((NKEYS + SCAN_CHUNK - 1) / SCAN_CHUNK)  // 157

typedef unsigned short ushort_t;
typedef __attribute__((ext_vector_type(8))) short bf16x8;
typedef __attribute__((ext_vector_type(8))) unsigned short ushort8_t;
typedef __attribute__((ext_vector_type(4))) unsigned short ushort4_t;
typedef __attribute__((ext_vector_type(4))) float f32x4;

__device__ __forceinline__ float b2f(ushort_t u) {
    return __uint_as_float(((unsigned int)u) << 16);
}
__device__ __forceinline__ ushort_t f2b(float f) {
    __hip_bfloat16 h = __float2bfloat16(f);
    return *reinterpret_cast<ushort_t*>(&h);
}

// ---------------- merged precompute: cvt + wqk + wagg + count + zeroing ----------------
__device__ __forceinline__ void prep_cvt(int i, const float* __restrict__ in, ushort_t* __restrict__ outp) {
    float4 v = *(const float4*)&in[(size_t)i * 4];
    ushort4 o;
    o.x = f2b(v.x); o.y = f2b(v.y); o.z = f2b(v.z); o.w = f2b(v.w);
    *(ushort4*)&outp[(size_t)i * 4] = o;
}

template <int D, int OUT>
__device__ __forceinline__ void prep_wqk(int tid, const float* __restrict__ w, const float* __restrict__ q,
                                         const float* __restrict__ k, ushort_t* __restrict__ wqkt) {
    int c = tid / D, i = tid % D;
    int r = c / 6, j = c % 6;
    const float* qk = (j < 3) ? q : k;
    int jj = (j < 3) ? j : j - 3;
    const float* wrow = w + ((size_t)r * D + i) * OUT;
    float s = 0.f;
    for (int o = 0; o < OUT; o++) s += wrow[o] * qk[o * 3 + jj];
    wqkt[(size_t)c * D + i] = f2b(s);
}

template <int D, int OC>
__device__ __forceinline__ void prep_wagg(int tid, const float* __restrict__ w, ushort_t* __restrict__ outp) {
    const int KT = RELS * 3 * D;
    int kidx = tid % KT;
    int o = tid / KT;
    int r = kidx / (3 * D), h = (kidx / D) % 3, i = kidx % D;
    outp[tid] = f2b(w[((size_t)r * D + i) * (3 * OC) + h * OC + o]);
}

#define PREP_N0 (N_NODES * EMB / 4)
#define PREP_N1 (48 * 128)
#define PREP_N2 (48 * 64)
#define PREP_N3 (64 * 3072)
#define PREP_N4 (16 * 1536)
#define PREP_N5 N_EDGES          // count
#define PREP_N6 (N_NODES * 16)   // zero x2pre (float4)
#define PREP_N7 (N_NODES * 4)    // zero outpre (float4)
#define PREP_TOT (PREP_N0 + PREP_N1 + PREP_N2 + PREP_N3 + PREP_N4 + PREP_N5 + PREP_N6 + PREP_N7)

__global__ __launch_bounds__(256) void k_prep(const float* __restrict__ emb, ushort_t* __restrict__ emb_b,
                                              const float* __restrict__ w1, const float* __restrict__ q1,
                                              const float* __restrict__ k1, ushort_t* __restrict__ wqkt1,
                                              const float* __restrict__ w2, const float* __restrict__ q2,
                                              const float* __restrict__ k2, ushort_t* __restrict__ wqkt2,
                                              ushort_t* __restrict__ wagg1, ushort_t* __restrict__ wagg2,
                                              const int* __restrict__ dstv, const int* __restrict__ etype,
                                              int* __restrict__ counts, float* __restrict__ x2pre,
                                              float* __restrict__ outpre) {
    int tid = blockIdx.x * 256 + threadIdx.x;
    if (tid < PREP_N0) { prep_cvt(tid, emb, emb_b); return; }
    tid -= PREP_N0;
    if (tid < PREP_N1) { prep_wqk<128, 192>(tid, w1, q1, k1, wqkt1); return; }
    tid -= PREP_N1;
    if (tid < PREP_N2) { prep_wqk<64, 48>(tid, w2, q2, k2, wqkt2); return; }
    tid -= PREP_N2;
    if (tid < PREP_N3) { prep_wagg<128, 64>(tid, w1, wagg1); return; }
    tid -= PREP_N3;
    if (tid < PREP_N4) { prep_wagg<64, 16>(tid, w2, wagg2); return; }
    tid -= PREP_N4;
    if (tid < PREP_N5) { atomicAdd(&counts[dstv[tid] * 8 + etype[tid]], 1); return; }
    tid -= PREP_N5;
    if (tid < PREP_N6) { *(float4*)&x2pre[(size_t)tid * 4] = make_float4(0.f, 0.f, 0.f, 0.f); return; }
    tid -= PREP_N6;
    if (tid < PREP_N7) { *(float4*)&outpre[(size_t)tid * 4] = make_float4(0.f, 0.f, 0.f, 0.f); return; }
}

// ---------------- hierarchical scan ----------------
__global__ __launch_bounds__(256) void k_scanA(const int* __restrict__ counts, int* __restrict__ keyoff,
                                               int* __restrict__ blocksum) {
    __shared__ int part[256];
    int b = blockIdx.x, tid = threadIdx.x;
    int base = b * SCAN_CHUNK + tid * 4;
    int4 c = make_int4(0, 0, 0, 0);
    if (base + 3 < NKEYS) c = *(const int4*)&counts[base];
    else {
        if (base + 0 < NKEYS) c.x = counts[base + 0];
        if (base + 1 < NKEYS) c.y = counts[base + 1];
        if (base + 2 < NKEYS) c.z = counts[base + 2];
        if (base + 3 < NKEYS) c.w = counts[base + 3];
    }
    int s = c.x + c.y + c.z + c.w;
    part[tid] = s;
    __syncthreads();
    for (int off = 1; off < 256; off <<= 1) {
        int v = (tid >= off) ? part[tid - off] : 0;
        __syncthreads();
        part[tid] += v;
        __syncthreads();
    }
    int excl = part[tid] - s;
    int4 o;
    o.x = excl;
    o.y = excl + c.x;
    o.z = excl + c.x + c.y;
    o.w = excl + c.x + c.y + c.z;
    if (base + 3 < NKEYS) *(int4*)&keyoff[base] = o;
    else {
        if (base + 0 < NKEYS) keyoff[base + 0] = o.x;
        if (base + 1 < NKEYS) keyoff[base + 1] = o.y;
        if (base + 2 < NKEYS) keyoff[base + 2] = o.z;
        if (base + 3 < NKEYS) keyoff[base + 3] = o.w;
    }
    if (tid == 255) blocksum[b] = part[255];
}

__global__ __launch_bounds__(256) void k_scanB(int* __restrict__ blocksum, int* __restrict__ blockbase,
                                               int* __restrict__ keyoff) {
    __shared__ int part[256];
    int tid = threadIdx.x;
    int v0 = (tid < SCAN_NBLK) ? blocksum[tid] : 0;
    part[tid] = v0;
    __syncthreads();
    for (int off = 1; off < 256; off <<= 1) {
        int v = (tid >= off) ? part[tid - off] : 0;
        __syncthreads();
        part[tid] += v;
        __syncthreads();
    }
    if (tid < SCAN_NBLK) blockbase[tid] = part[tid] - v0;
    if (tid == 255) keyoff[NKEYS] = part[255];
}

__global__ __launch_bounds__(256) void k_scanC(const int* __restrict__ blockbase, int* __restrict__ keyoff,
                                               int* __restrict__ cursor) {
    int b = blockIdx.x, tid = threadIdx.x;
    int base = b * SCAN_CHUNK + tid * 4;
    int add = blockbase[b];
    if (base + 3 < NKEYS) {
        int4 v = *(const int4*)&keyoff[base];
        v.x += add; v.y += add; v.z += add; v.w += add;
        *(int4*)&keyoff[base] = v;
        *(int4*)&cursor[base] = v;
    } else {
        for (int j = 0; j < 4; j++) {
            if (base + j < NKEYS) {
                int v = keyoff[base + j] + add;
                keyoff[base + j] = v;
                cursor[base + j] = v;
            }
        }
    }
}

// ---------------- scatter srcs into CSR order ----------------
__global__ __launch_bounds__(256) void k_scatter(const int* __restrict__ src, const int* __restrict__ dst,
                                                 const int* __restrict__ et, int* __restrict__ cursor,
                                                 int* __restrict__ srcs) {
    int e = blockIdx.x * blockDim.x + threadIdx.x;
    if (e < N_EDGES) {
        int p = atomicAdd(&cursor[dst[e] * 8 + et[e]], 1);
        srcs[p] = src[e];
    }
}

// ---------------- direct-fragment MFMA GEMM (layer-1 qkd projection) ----------------
template <int K, int KCH, int N, int MREP, int NREP>
__global__ __launch_bounds__(256) void k_mfma_gemm(const ushort_t* __restrict__ A, const ushort_t* __restrict__ Bt,
                                                   float* __restrict__ outp, int M) {
    const int wid = threadIdx.x >> 6;
    const int lane = threadIdx.x & 63;
    const int m0 = blockIdx.x * (4 * MREP * 16) + wid * (MREP * 16);
    const int kbase = blockIdx.y * KCH;
    const int l15 = lane & 15;
    const int kq = (lane >> 4) * 8;

    f32x4 acc[MREP][NREP] = {};
    for (int kk = kbase; kk < kbase + KCH; kk += 32) {
        bf16x8 a[MREP], b[NREP];
#pragma unroll
        for (int i = 0; i < MREP; i++) {
            int row = m0 + i * 16 + l15;
            row = row < M ? row : M - 1;
            a[i] = *(const bf16x8*)&A[(size_t)row * K + kk + kq];
        }
#pragma unroll
        for (int j = 0; j < NREP; j++) b[j] = *(const bf16x8*)&Bt[(size_t)(j * 16 + l15) * K + kk + kq];
#pragma unroll
        for (int i = 0; i < MREP; i++)
#pragma unroll
            for (int j = 0; j < NREP; j++)
                acc[i][j] = __builtin_amdgcn_mfma_f32_16x16x32_bf16(a[i], b[j], acc[i][j], 0, 0, 0);
    }
    float* op = outp + (size_t)blockIdx.y * M * N;
    const int r4 = (lane >> 4) * 4;
#pragma unroll
    for (int i = 0; i < MREP; i++) {
#pragma unroll
        for (int j = 0; j < NREP; j++) {
#pragma unroll
            for (int g = 0; g < 4; g++) {
                int row = m0 + i * 16 + r4 + g;
                if (row < M) op[(size_t)row * N + j * 16 + l15] = acc[i][j][g];
            }
        }
    }
}

// ---------------- layer-2 qkd GEMM with fused bias+relu epilogue-prologue ----------------
__global__ __launch_bounds__(256) void k_gemm2f(const float* __restrict__ x2pre, const float* __restrict__ bias,
                                                const ushort_t* __restrict__ Bt, ushort_t* __restrict__ x2,
                                                float* __restrict__ qkd) {
    const int wid = threadIdx.x >> 6;
    const int lane = threadIdx.x & 63;
    const int m0 = blockIdx.x * 64 + wid * 16;
    const int l15 = lane & 15;
    const int kq = (lane >> 4) * 8;

    f32x4 acc[3] = {};
#pragma unroll
    for (int kk = 0; kk < 64; kk += 32) {
        int row = m0 + l15;
        row = row < N_NODES ? row : N_NODES - 1;
        int col = kk + kq;
        float4 f0 = *(const float4*)&x2pre[(size_t)row * 64 + col];
        float4 f1 = *(const float4*)&x2pre[(size_t)row * 64 + col + 4];
        float fv[8] = {f0.x, f0.y, f0.z, f0.w, f1.x, f1.y, f1.z, f1.w};
        bf16x8 av;
#pragma unroll
        for (int c = 0; c < 8; c++) {
            float s = fv[c] + bias[col + c];
            s = s > 0.f ? s : 0.f;
            av[c] = (short)f2b(s);
        }
        *(bf16x8*)&x2[(size_t)row * 64 + col] = av;
#pragma unroll
        for (int j = 0; j < 3; j++) {
            bf16x8 bv = *(const bf16x8*)&Bt[(size_t)(j * 16 + l15) * 64 + col];
            acc[j] = __builtin_amdgcn_mfma_f32_16x16x32_bf16(av, bv, acc[j], 0, 0, 0);
        }
    }
    const int r4 = (lane >> 4) * 4;
#pragma unroll
    for (int j = 0; j < 3; j++) {
#pragma unroll
        for (int g = 0; g < 4; g++) {
            int row = m0 + r4 + g;
            if (row < N_NODES) qkd[(size_t)row * 48 + j * 16 + l15] = acc[j][g];
        }
    }
}

// ---------------- per-edge alpha from qkd (on the fly), also returns src ----------------
__device__ __forceinline__ void edge_alpha(int s_idx, const int (&ko)[9], const int* __restrict__ srcs,
                                           const float* __restrict__ qkd, const float* __restrict__ qbase,
                                           float& a0, float& a1, float& a2, int& sv) {
    int r = 0;
#pragma unroll
    for (int j = 1; j < 8; j++) r += (s_idx >= ko[j]) ? 1 : 0;
    sv = srcs[s_idx];
    const float* kd = qkd + (size_t)sv * 48 + r * 6 + 3;
    const float* qd = qbase + r * 6;
    float t0 = qd[0] + kd[0], t1 = qd[1] + kd[1], t2 = qd[2] + kd[2];
    a0 = t0 > 0.f ? t0 : NEG * t0;
    a1 = t1 > 0.f ? t1 : NEG * t1;
    a2 = t2 > 0.f ? t2 : NEG * t2;
}

__device__ __forceinline__ ushort4_t pack_svw(int sv, float w0, float w1, float w2) {
    ushort4_t v;
    v[0] = (ushort_t)sv;
    v[1] = f2b(w0);
    v[2] = f2b(w1);
    v[3] = f2b(w2);
    return v;
}

// ---------------- softmax stats -> packed svw8[e] ----------------
__global__ __launch_bounds__(256) void k_stats(const int* __restrict__ keyoff, const int* __restrict__ srcs,
                                               const float* __restrict__ qkd, ushort4_t* __restrict__ svw8) {
    int node = blockIdx.x * 4 + (threadIdx.x >> 6);
    int lane = threadIdx.x & 63;
    int ko[9];
#pragma unroll
    for (int j = 0; j < 9; j++) ko[j] = keyoff[node * 8 + j];
    int beg = ko[0], end = ko[8], deg = end - beg;
    if (deg == 0) return;
    const float* qbase = qkd + (size_t)node * 48;

    if (deg <= 64) {
        float a0 = -INFINITY, a1 = -INFINITY, a2 = -INFINITY;
        int sv = 0;
        if (lane < deg) edge_alpha(beg + lane, ko, srcs, qkd, qbase, a0, a1, a2, sv);
        float m0 = a0, m1 = a1, m2 = a2;
#pragma unroll
        for (int off = 32; off >= 1; off >>= 1) {
            m0 = fmaxf(m0, __shfl_xor(m0, off));
            m1 = fmaxf(m1, __shfl_xor(m1, off));
            m2 = fmaxf(m2, __shfl_xor(m2, off));
        }
        float e0 = 0.f, e1 = 0.f, e2 = 0.f;
        if (lane < deg) {
            e0 = expf(a0 - m0);
            e1 = expf(a1 - m1);
            e2 = expf(a2 - m2);
        }
        float s0 = e0, s1 = e1, s2 = e2;
#pragma unroll
        for (int off = 32; off >= 1; off >>= 1) {
            s0 += __shfl_xor(s0, off);
            s1 += __shfl_xor(s1, off);
            s2 += __shfl_xor(s2, off);
        }
        float i0 = 1.f / (3.f * (s0 + 1e-16f));
        float i1 = 1.f / (3.f * (s1 + 1e-16f));
        float i2 = 1.f / (3.f * (s2 + 1e-16f));
        if (lane < deg) svw8[beg + lane] = pack_svw(sv, e0 * i0, e1 * i1, e2 * i2);
    } else {
        float m0 = -INFINITY, m1 = -INFINITY, m2 = -INFINITY;
        for (int i = beg + lane; i < end; i += 64) {
            float a0, a1, a2; int sv;
            edge_alpha(i, ko, srcs, qkd, qbase, a0, a1, a2, sv);
            m0 = fmaxf(m0, a0); m1 = fmaxf(m1, a1); m2 = fmaxf(m2, a2);
        }
#pragma unroll
        for (int off = 32; off >= 1; off >>= 1) {
            m0 = fmaxf(m0, __shfl_xor(m0, off));
            m1 = fmaxf(m1, __shfl_xor(m1, off));
            m2 = fmaxf(m2, __shfl_xor(m2, off));
        }
        float s0 = 0.f, s1 = 0.f, s2 = 0.f;
        for (int i = beg + lane; i < end; i += 64) {
            float a0, a1, a2; int sv;
            edge_alpha(i, ko, srcs, qkd, qbase, a0, a1, a2, sv);
            s0 += expf(a0 - m0); s1 += expf(a1 - m1); s2 += expf(a2 - m2);
        }
#pragma unroll
        for (int off = 32; off >= 1; off >>= 1) {
            s0 += __shfl_xor(s0, off);
            s1 += __shfl_xor(s1, off);
            s2 += __shfl_xor(s2, off);
        }
        float i0 = 1.f / (3.f * (s0 + 1e-16f));
        float i1 = 1.f / (3.f * (s1 + 1e-16f));
        float i2 = 1.f / (3.f * (s2 + 1e-16f));
        for (int i = beg + lane; i < end; i += 64) {
            float a0, a1, a2; int sv;
            edge_alpha(i, ko, srcs, qkd, qbase, a0, a1, a2, sv);
            svw8[i] = pack_svw(sv, expf(a0 - m0) * i0, expf(a1 - m1) * i1, expf(a2 - m2) * i2);
        }
    }
}

__device__ __forceinline__ ushort4_t fetch_svw(const ushort4_t* __restrict__ svw8, int beg, int safe, int deg,
                                               int s) {
    ushort4_t v = svw8[s < deg ? beg + s : safe];
    if (s >= deg) { v[1] = 0; v[2] = 0; v[3] = 0; }
    return v;
}

// ---------------- FUSED layer 1 v12: dual independent chains per quarter-wave ----------------
// grid (625, 8). 32 nodes/block: quarter-wave handles node n (chain A) and n+16 (chain B).
#define PADK1 408
__global__ __launch_bounds__(256) void k_fused1(const int* __restrict__ keyoff, const ushort4_t* __restrict__ svw8,
                                                const ushort_t* __restrict__ x, const ushort_t* __restrict__ wagg,
                                                float* __restrict__ x2pre) {
    __shared__ ushort_t lt[32][PADK1];  // 25.5 KB
    const int tid = threadIdx.x;
    const int w = tid >> 6, lane = tid & 63;
    const int q15 = lane & 15, kq = (lane >> 4) * 8;
    const int l15 = lane & 15;
    const int nbase = blockIdx.x * 32;
    const int r = blockIdx.y;
    const int mynode = w * 4 + (lane >> 4);  // 0..15
    const int keyA = (nbase + mynode) * 8 + r;
    const int keyB = (nbase + 16 + mynode) * 8 + r;

    const int begA = keyoff[keyA], endA = keyoff[keyA + 1];
    const int begB = keyoff[keyB], endB = keyoff[keyB + 1];
    const int degA = endA - begA, degB = endB - begB;
    const int mdeg = degA > degB ? degA : degB;
    const int safeA = begA < N_EDGES ? begA : 0;
    const int safeB = begB < N_EDGES ? begB : 0;

    float aA0[8] = {}, aA1[8] = {}, aA2[8] = {};
    float aB0[8] = {}, aB1[8] = {}, aB2[8] = {};
    if (mdeg > 0) {
        ushort4_t swA0 = fetch_svw(svw8, begA, safeA, degA, 0);
        ushort4_t swB0 = fetch_svw(svw8, begB, safeB, degB, 0);
        ushort4_t swA1 = fetch_svw(svw8, begA, safeA, degA, 1);
        ushort4_t swB1 = fetch_svw(svw8, begB, safeB, degB, 1);
        ushort8_t xvA0 = *(const ushort8_t*)&x[(size_t)swA0[0] * 128 + q15 * 8];
        ushort8_t xvB0 = *(const ushort8_t*)&x[(size_t)swB0[0] * 128 + q15 * 8];
        for (int i = 0; i < mdeg; i++) {
            ushort4_t swA2 = fetch_svw(svw8, begA, safeA, degA, i + 2);
            ushort4_t swB2 = fetch_svw(svw8, begB, safeB, degB, i + 2);
            ushort8_t xvA1 = *(const ushort8_t*)&x[(size_t)swA1[0] * 128 + q15 * 8];
            ushort8_t xvB1 = *(const ushort8_t*)&x[(size_t)swB1[0] * 128 + q15 * 8];
            float wA0 = b2f(swA0[1]), wA1 = b2f(swA0[2]), wA2 = b2f(swA0[3]);
            float wB0 = b2f(swB0[1]), wB1 = b2f(swB0[2]), wB2 = b2f(swB0[3]);
#pragma unroll
            for (int c = 0; c < 8; c++) {
                float fA = b2f(xvA0[c]);
                aA0[c] += wA0 * fA;
                aA1[c] += wA1 * fA;
                aA2[c] += wA2 * fA;
                float fB = b2f(xvB0[c]);
                aB0[c] += wB0 * fB;
                aB1[c] += wB1 * fB;
                aB2[c] += wB2 * fB;
            }
            swA0 = swA1; swA1 = swA2; xvA0 = xvA1;
            swB0 = swB1; swB1 = swB2; xvB0 = xvB1;
        }
    }
    {
        ushort8_t oA0, oA1, oA2, oB0, oB1, oB2;
#pragma unroll
        for (int c = 0; c < 8; c++) {
            oA0[c] = f2b(aA0[c]); oA1[c] = f2b(aA1[c]); oA2[c] = f2b(aA2[c]);
            oB0[c] = f2b(aB0[c]); oB1[c] = f2b(aB1[c]); oB2[c] = f2b(aB2[c]);
        }
        *(ushort8_t*)&lt[mynode][0 * 128 + q15 * 8] = oA0;
        *(ushort8_t*)&lt[mynode][1 * 128 + q15 * 8] = oA1;
        *(ushort8_t*)&lt[mynode][2 * 128 + q15 * 8] = oA2;
        *(ushort8_t*)&lt[16 + mynode][0 * 128 + q15 * 8] = oB0;
        *(ushort8_t*)&lt[16 + mynode][1 * 128 + q15 * 8] = oB1;
        *(ushort8_t*)&lt[16 + mynode][2 * 128 + q15 * 8] = oB2;
    }
    __syncthreads();

    f32x4 accA = {}, accB = {};
#pragma unroll
    for (int ks = 0; ks < 12; ks++) {
        bf16x8 bv = *(const bf16x8*)&wagg[(size_t)(w * 16 + l15) * 3072 + r * 384 + ks * 32 + kq];
        bf16x8 avA = *(const bf16x8*)&lt[l15][ks * 32 + kq];
        bf16x8 avB = *(const bf16x8*)&lt[16 + l15][ks * 32 + kq];
        accA = __builtin_amdgcn_mfma_f32_16x16x32_bf16(avA, bv, accA, 0, 0, 0);
        accB = __builtin_amdgcn_mfma_f32_16x16x32_bf16(avB, bv, accB, 0, 0, 0);
    }
    const int r4 = (lane >> 4) * 4;
#pragma unroll
    for (int g = 0; g < 4; g++) {
        atomicAdd(&x2pre[(size_t)(nbase + r4 + g) * 64 + w * 16 + l15], accA[g]);
        atomicAdd(&x2pre[(size_t)(nbase + 16 + r4 + g) * 64 + w * 16 + l15], accB[g]);
    }
}

// ---------------- FUSED layer 2 v12: dual chains, 32 nodes/block ----------------
#define PADK2 208
__global__ __launch_bounds__(256) void k_fused2(const int* __restrict__ keyoff, const ushort4_t* __restrict__ svw8,
                                                const ushort_t* __restrict__ x2in, const ushort_t* __restrict__ wagg,
                                                float* __restrict__ outpre) {
    __shared__ ushort_t lt[32][PADK2];  // 13 KB
    const int tid = threadIdx.x;
    const int w = tid >> 6, lane = tid & 63;
    const int q15 = lane & 15, kq = (lane >> 4) * 8;
    const int l15 = lane & 15;
    const int nbase = blockIdx.x * 32;
    const int r = blockIdx.y;
    const int mynode = w * 4 + (lane >> 4);
    const int keyA = (nbase + mynode) * 8 + r;
    const int keyB = (nbase + 16 + mynode) * 8 + r;

    const int begA = keyoff[keyA], endA = keyoff[keyA + 1];
    const int begB = keyoff[keyB], endB = keyoff[keyB + 1];
    const int degA = endA - begA, degB = endB - begB;
    const int mdeg = degA > degB ? degA : degB;
    const int safeA = begA < N_EDGES ? begA : 0;
    const int safeB = begB < N_EDGES ? begB : 0;

    float aA0[4] = {}, aA1[4] = {}, aA2[4] = {};
    float aB0[4] = {}, aB1[4] = {}, aB2[4] = {};
    if (mdeg > 0) {
        ushort4_t swA0 = fetch_svw(svw8, begA, safeA, degA, 0);
        ushort4_t swB0 = fetch_svw(svw8, begB, safeB, degB, 0);
        ushort4_t swA1 = fetch_svw(svw8, begA, safeA, degA, 1);
        ushort4_t swB1 = fetch_svw(svw8, begB, safeB, degB, 1);
        ushort4_t xvA0 = *(const ushort4_t*)&x2in[(size_t)swA0[0] * 64 + q15 * 4];
        ushort4_t xvB0 = *(const ushort4_t*)&x2in[(size_t)swB0[0] * 64 + q15 * 4];
        for (int i = 0; i < mdeg; i++) {
            ushort4_t swA2 = fetch_svw(svw8, begA, safeA, degA, i + 2);
            ushort4_t swB2 = fetch_svw(svw8, begB, safeB, degB, i + 2);
            ushort4_t xvA1 = *(const ushort4_t*)&x2in[(size_t)swA1[0] * 64 + q15 * 4];
            ushort4_t xvB1 = *(const ushort4_t*)&x2in[(size_t)swB1[0] * 64 + q15 * 4];
            float wA0 = b2f(swA0[1]), wA1 = b2f(swA0[2]), wA2 = b2f(swA0[3]);
            float wB0 = b2f(swB0[1]), wB1 = b2f(swB0[2]), wB2 = b2f(swB0[3]);
#pragma unroll
            for (int c = 0; c < 4; c++) {
                float fA = b2f(xvA0[c]);
                aA0[c] += wA0 * fA;
                aA1[c] += wA1 * fA;
                aA2[c] += wA2 * fA;
                float fB = b2f(xvB0[c]);
                aB0[c] += wB0 * fB;
                aB1[c] += wB1 * fB;
                aB2[c] += wB2 * fB;
            }
            swA0 = swA1; swA1 = swA2; xvA0 = xvA1;
            swB0 = swB1; swB1 = swB2; xvB0 = xvB1;
        }
    }
    {
        ushort4_t oA0, oA1, oA2, oB0, oB1, oB2;
#pragma unroll
        for (int c = 0; c < 4; c++) {
            oA0[c] = f2b(aA0[c]); oA1[c] = f2b(aA1[c]); oA2[c] = f2b(aA2[c]);
            oB0[c] = f2b(aB0[c]); oB1[c] = f2b(aB1[c]); oB2[c] = f2b(aB2[c]);
        }
        *(ushort4_t*)&lt[mynode][0 * 64 + q15 * 4] = oA0;
        *(ushort4_t*)&lt[mynode][1 * 64 + q15 * 4] = oA1;
        *(ushort4_t*)&lt[mynode][2 * 64 + q15 * 4] = oA2;
        *(ushort4_t*)&lt[16 + mynode][0 * 64 + q15 * 4] = oB0;
        *(ushort4_t*)&lt[16 + mynode][1 * 64 + q15 * 4] = oB1;
        *(ushort4_t*)&lt[16 + mynode][2 * 64 + q15 * 4] = oB2;
    }
    __syncthreads();

    if (w < 2) {
        const int tb = w * 16;  // tile base row in lt
        f32x4 acc = {};
#pragma unroll
        for (int ks = 0; ks < 6; ks++) {
            bf16x8 av = *(const bf16x8*)&lt[tb + l15][ks * 32 + kq];
            bf16x8 bv = *(const bf16x8*)&wagg[(size_t)l15 * 1536 + r * 192 + ks * 32 + kq];
            acc = __builtin_amdgcn_mfma_f32_16x16x32_bf16(av, bv, acc, 0, 0, 0);
        }
        const int r4 = (lane >> 4) * 4;
#pragma unroll
        for (int g = 0; g < 4; g++)
            atomicAdd(&outpre[(size_t)(nbase + tb + r4 + g) * 16 + l15], acc[g]);
    }
}

// ---------------- bias + sigmoid -> out f32 ----------------
__global__ __launch_bounds__(256) void k_reduce2(const float* __restrict__ outpre, const float* __restrict__ bias,
                                                 float* __restrict__ outp) {
    int idx = blockIdx.x * blockDim.x + threadIdx.x;
    const int MN = N_NODES * 16;
    if (idx >= MN) return;
    float s = outpre[idx] + bias[idx & 15];
    outp[idx] = 1.f / (1.f + expf(-s));
}

extern "C" void kernel_launch(void* const* d_in, const int* in_sizes, int n_in, void* d_out, int out_size,
                              void* d_ws, size_t ws_size, hipStream_t stream) {
    const float* emb = (const float*)d_in[0];
    const float* w1 = (const float*)d_in[1];
    const float* q1 = (const float*)d_in[2];
    const float* k1 = (const float*)d_in[3];
    const float* b1 = (const float*)d_in[4];
    const float* w2 = (const float*)d_in[5];
    const float* q2 = (const float*)d_in[6];
    const float* k2 = (const float*)d_in[7];
    const float* b2 = (const float*)d_in[8];
    const int* eidx = (const int*)d_in[9];
    const int* etype = (const int*)d_in[10];
    const int* srcv = eidx;
    const int* dstv = eidx + N_EDGES;
    float* out = (float*)d_out;

    char* p = (char*)d_ws;
    auto alloc = [&](size_t bytes) -> void* {
        void* q = p;
        p += (bytes + 255) & ~(size_t)255;
        return q;
    };
    int* counts = (int*)alloc((size_t)NKEYS * 4);
    int* keyoff = (int*)alloc((size_t)(NKEYS + 1) * 4);
    int* cursor = (int*)alloc((size_t)NKEYS * 4);
    int* blocksum = (int*)alloc((size_t)SCAN_NBLK * 4);
    int* blockbase = (int*)alloc((size_t)SCAN_NBLK * 4);
    int* srcs = (int*)alloc((size_t)N_EDGES * 4);
    ushort4_t* svw8 = (ushort4_t*)alloc((size_t)N_EDGES * 8);
    ushort_t* emb_b = (ushort_t*)alloc((size_t)N_NODES * EMB * 2);
    ushort_t* wqkt1 = (ushort_t*)alloc((size_t)48 * 128 * 2);
    ushort_t* wagg1 = (ushort_t*)alloc((size_t)64 * 3072 * 2);
    ushort_t* wqkt2 = (ushort_t*)alloc((size_t)48 * 64 * 2);
    ushort_t* wagg2 = (ushort_t*)alloc((size_t)16 * 1536 * 2);
    float* qkd = (float*)alloc((size_t)N_NODES * 48 * 4);
    ushort_t* x2 = (ushort_t*)alloc((size_t)N_NODES * 64 * 2);
    float* x2pre = (float*)alloc((size_t)N_NODES * 64 * 4);
    float* outpre = (float*)alloc((size_t)N_NODES * 16 * 4);

    hipMemsetAsync(counts, 0, (size_t)NKEYS * 4, stream);
    k_prep<<<(PREP_TOT + 255) / 256, 256, 0, stream>>>(emb, emb_b, w1, q1, k1, wqkt1, w2, q2, k2, wqkt2, wagg1,
                                                       wagg2, dstv, etype, counts, x2pre, outpre);

    // ---- CSR over (dst, rel) ----
    k_scanA<<<SCAN_NBLK, 256, 0, stream>>>(counts, keyoff, blocksum);
    k_scanB<<<1, 256, 0, stream>>>(blocksum, blockbase, keyoff);
    k_scanC<<<SCAN_NBLK, 256, 0, stream>>>(blockbase, keyoff, cursor);
    k_scatter<<<(N_EDGES + 255) / 256, 256, 0, stream>>>(srcv, dstv, etype, cursor, srcs);

    // ---- layer 1 ----
    k_mfma_gemm<128, 128, 48, 1, 3><<<dim3(313, 1), 256, 0, stream>>>(emb_b, wqkt1, qkd, N_NODES);
    k_stats<<<N_NODES / 4, 256, 0, stream>>>(keyoff, srcs, qkd, svw8);
    k_fused1<<<dim3(N_NODES / 32, 8), 256, 0, stream>>>(keyoff, svw8, emb_b, wagg1, x2pre);

    // ---- layer 2 (bias+relu fused into qkd GEMM) ----
    k_gemm2f<<<dim3(313), 256, 0, stream>>>(x2pre, b1, wqkt2, x2, qkd);
    k_stats<<<N_NODES / 4, 256, 0, stream>>>(keyoff, srcs, qkd, svw8);
    k_fused2<<<dim3(N_NODES / 32, 8), 256, 0, stream>>>(keyoff, svw8, x2, wagg2, outpre);
    k_reduce2<<<(N_NODES * 16 + 255) / 256, 256, 0, stream>>>(outpre, b2, out);
}